// Round 14
// baseline (264.312 us; speedup 1.0000x reference)
//
#include <hip/hip_runtime.h>
#include <hip/hip_bf16.h>

#define N 768
#define IN_DIM 128
#define HID 256
#define HD 32
#define TJ 32
#define NT (N / TJ)
#define SCALE_INV 0.17677669529663687f  // 1/sqrt(32)

typedef short s16x8 __attribute__((ext_vector_type(8)));
typedef float f32x4 __attribute__((ext_vector_type(4)));

__device__ __forceinline__ float bf2f(unsigned short s) {
    return __uint_as_float(((unsigned)s) << 16);
}
__device__ __forceinline__ unsigned short bf_bits(float f) {
    __hip_bfloat16 h = __float2bfloat16(f);
    union { __hip_bfloat16 h; unsigned short u; } c; c.h = h; return c.u;
}
__device__ __forceinline__ unsigned cvt2(float a, float b) {
    __hip_bfloat162 h2 = __float22bfloat162_rn(make_float2(a, b));
    union { __hip_bfloat162 h; unsigned u; } c; c.h = h2; return c.u;
}

// LDS-only barrier: waits own-wave LDS ops, leaves global loads in flight.
#define BAR_LDS() do { asm volatile("s_waitcnt lgkmcnt(0)" ::: "memory"); \
                       __builtin_amdgcn_s_barrier(); } while (0)

// ---------------------------------------------------------------------------
// kernel 1 (grid 1024):
//  blocks 0..767   : per-i prep -> Q f32; Kt = K^T f32; Vt = V^T bf16;
//                    A = pos@W1 f32; w3q fragments for row i
//  blocks 768..1023: pack W2 into MFMA B-frag order + transpose Wo
// ---------------------------------------------------------------------------
__global__ __launch_bounds__(256) void prep_kernel(
    const float* __restrict__ x, const float* __restrict__ pos,
    const float* __restrict__ Wq, const float* __restrict__ bq,
    const float* __restrict__ Wk, const float* __restrict__ bk,
    const float* __restrict__ Wv, const float* __restrict__ bv,
    const float* __restrict__ W1, const float* __restrict__ W2,
    const float* __restrict__ W3, const float* __restrict__ Wo,
    float* __restrict__ Q, float* __restrict__ Kt,
    unsigned short* __restrict__ Vt, float* __restrict__ A,
    unsigned short* __restrict__ w2f, float* __restrict__ WoT,
    unsigned short* __restrict__ w3qg)
{
    const int bx = blockIdx.x, t = threadIdx.x;
    __shared__ float xs[IN_DIM];
    __shared__ float ps[3];
    __shared__ float qrow[HID];

    if (bx >= N) {
        // pack W2 B-frags: w2f[((s*16+nt)*64+l)*8+e] = W2[32s+8(l>>4)+e][16nt+(l&15)]
        const int p = (bx - N) * 256 + t;               // 0..65535
        const int e = p & 7, l = (p >> 3) & 63, nt = (p >> 9) & 15, s = p >> 13;
        const int krow = 32 * s + 8 * (l >> 4) + e;     // contraction index
        const int ncol = 16 * nt + (l & 15);            // output n index
        w2f[p] = bf_bits(W2[krow * HID + ncol]);
        WoT[p] = Wo[(p & 255) * HID + (p >> 8)];        // WoT[t][k] = Wo[k][t]
        return;
    }

    const int i = bx;
    if (t < IN_DIM) xs[t] = x[i * IN_DIM + t];
    if (t < 3) ps[t] = pos[i * 3 + t];
    __syncthreads();
    float q = bq[t], k = bk[t], v = bv[t];
#pragma unroll 8
    for (int kk = 0; kk < IN_DIM; ++kk) {
        const float xv = xs[kk];
        q += xv * Wq[kk * HID + t];
        k += xv * Wk[kk * HID + t];
        v += xv * Wv[kk * HID + t];
    }
    const float a = ps[0] * W1[t] + ps[1] * W1[HID + t] + ps[2] * W1[2 * HID + t];
    Q[i * HID + t] = q;
    Kt[(size_t)t * N + i] = k;
    Vt[(size_t)t * N + i] = bf_bits(v);
    A[i * HID + t] = a;
    qrow[t] = q;
    __syncthreads();

    // w3q frags: w3q[h][k] = sum_d W3[k][d]*q[h*32+d], B-frag order
    const int l = t & 63, sp = t >> 6, lg = l >> 4, hh = l & 15;
#pragma unroll
    for (int ss = 0; ss < 2; ++ss) {
        const int s = 2 * sp + ss;
        s16x8 frag = {0, 0, 0, 0, 0, 0, 0, 0};
        if (hh < 8) {
#pragma unroll
            for (int e = 0; e < 8; ++e) {
                const int kk = 32 * s + 8 * lg + e;
                const float* w3p = W3 + kk * HD;
                float acc = 0.f;
#pragma unroll
                for (int d0 = 0; d0 < 32; d0 += 4) {
                    const float4 wv = *(const float4*)(w3p + d0);
                    acc += wv.x * qrow[hh * HD + d0] + wv.y * qrow[hh * HD + d0 + 1]
                         + wv.z * qrow[hh * HD + d0 + 2] + wv.w * qrow[hh * HD + d0 + 3];
                }
                frag[e] = (short)bf_bits(acc);
            }
        }
        *(s16x8*)(w3qg + (size_t)i * 4096 + (size_t)(s * 64 + l) * 8) = frag;
    }
}

// ---------------------------------------------------------------------------
// kernel 2: S1[h][i][j] = q_i,h . k_j,h (f32). 32 i x 64 j x 8 h per block.
// ---------------------------------------------------------------------------
__global__ __launch_bounds__(256) void s1_kernel(
    const float* __restrict__ Q, const float* __restrict__ Kt,
    float* __restrict__ S1)
{
    const int t = threadIdx.x;
    const int i0 = (blockIdx.x / 12) * 32;
    const int j0 = (blockIdx.x % 12) * 64;
    __shared__ float qTs[256 * 36];   // [d'][i], row stride 36, XOR-swizzled chunks

    {
        const int iq = t & 31;
        const int dbase = (t >> 5) * 32;
        const int xk = t >> 5;
        const int colsw = (((iq >> 2) ^ xk) << 2) + (iq & 3);
        const float* qp = Q + (size_t)(i0 + iq) * HID + dbase;
#pragma unroll
        for (int cc = 0; cc < 8; ++cc) {
            const float4 qv = *(const float4*)(qp + 4 * cc);
            qTs[(dbase + 4 * cc + 0) * 36 + colsw] = qv.x;
            qTs[(dbase + 4 * cc + 1) * 36 + colsw] = qv.y;
            qTs[(dbase + 4 * cc + 2) * 36 + colsw] = qv.z;
            qTs[(dbase + 4 * cc + 3) * 36 + colsw] = qv.w;
        }
    }
    __syncthreads();

    const int h = t >> 5, jj = t & 31;
    const int j1 = j0 + jj, j2 = j0 + jj + 32;
    f32x4 acc0[8] = {}, acc1[8] = {};
    const float* kp = Kt + (size_t)(32 * h) * N + j1;
#pragma unroll 4
    for (int d = 0; d < 32; ++d) {
        const float k0 = kp[(size_t)d * N];
        const float k1 = kp[(size_t)d * N + 32];
        const float* qrow = &qTs[(32 * h + d) * 36];
#pragma unroll
        for (int ic = 0; ic < 8; ++ic) {
            const f32x4 qv = *(const f32x4*)&qrow[(ic ^ h) << 2];
            acc0[ic] += qv * k0;
            acc1[ic] += qv * k1;
        }
    }
    float* op = S1 + (size_t)h * (N * N) + (size_t)i0 * N;
#pragma unroll
    for (int ic = 0; ic < 8; ++ic)
#pragma unroll
        for (int u = 0; u < 4; ++u) {
            op[(size_t)(4 * ic + u) * N + j1] = acc0[ic][u];
            op[(size_t)(4 * ic + u) * N + j2] = acc1[ic][u];
        }
}

// ---------------------------------------------------------------------------
// kernel 3: fused main — r13 phase structure at TJ=32. LDS ~45 KB ->
// 3 blocks/CU (LDS-limited; VGPR ~124 allows 4 waves/SIMD). 4 LDS-only
// barriers/tile, 24 tiles. Phase A: wave w covers (mt=w&1, s=4*(w>>1)..+3).
// Phase B: mt-outer (2 mt), bias-seeded acc, bfr[32] dies at B end.
// Phase C: waves 0-1. p-gen: half-wave (lane<32 -> head w, else w+4).
// ---------------------------------------------------------------------------
__global__ __launch_bounds__(256, 2) void fused_main_kernel(
    const float* __restrict__ Ag, const float* __restrict__ S1,
    const unsigned short* __restrict__ Vt,
    const unsigned short* __restrict__ w2fg, const unsigned short* __restrict__ w3qg,
    const float* __restrict__ b1, const float* __restrict__ b2,
    const float* __restrict__ WoT, const float* __restrict__ bo,
    float* __restrict__ out)
{
    const int i = blockIdx.x, t = threadIdx.x;
    const int w = t >> 6, l = t & 63;
    const int lg = l >> 4, l15 = l & 15;

    __shared__ __align__(16) short h1f[2 * 8 * 64 * 8];   // 16 KB  H1 A-frags
    __shared__ __align__(16) short h2s[32 * 264];          // 16.9 KB H2 [j][k]
    __shared__ __align__(16) short w3qf[8 * 64 * 8];       // 8 KB   w3q B-frags
    __shared__ __align__(16) float slds[8 * 36];           // scores [h][jj]
    __shared__ __align__(16) float plds[8 * 36];           // probs  [h][jj]
    __shared__ float basek[HID];
    __shared__ float hm[8], hpsum[8], hresc[8];
    float* const oa = slds;                                // epilogue overlay

    // ---------------- prolog
    basek[t] = b1[t] - Ag[(size_t)i * HID + t];
    {
        const int c0 = t, c1 = t + 256;
        *(s16x8*)&w3qf[c0 * 8] = *(const s16x8*)(w3qg + (size_t)i * 4096 + (size_t)c0 * 8);
        *(s16x8*)&w3qf[c1 * 8] = *(const s16x8*)(w3qg + (size_t)i * 4096 + (size_t)c1 * 8);
    }
    if (t < 8) { hm[t] = -3.0e38f; hpsum[t] = 0.f; }
    float bias[4];
#pragma unroll
    for (int n = 0; n < 4; ++n) bias[n] = b2[64 * w + 16 * n + l15];

    float pv = 0.f;
    const int h = t >> 5;                    // PV head of this thread
    const int mtA = w & 1;                   // phase-A mt-block
    const int sB = (w >> 1) * 4;             // phase-A s-slice base
    const unsigned short* vrow = Vt + (size_t)t * N;
    BAR_LDS();

#pragma unroll 1
    for (int tile = 0; tile < NT; ++tile) {
        const int j0 = tile * TJ;

        // ---- phase A: H1 = relu(A[j] - A[i] + b1) in A-fragment order
        {
            const int jj = 16 * mtA + l15;
            const float* ap = Ag + (size_t)(j0 + jj) * HID + 8 * lg;
#pragma unroll
            for (int ss = 0; ss < 4; ++ss) {
                const int s = sB + ss;
                const float4 a0 = *(const float4*)(ap + 32 * s);
                const float4 a1 = *(const float4*)(ap + 32 * s + 4);
                const float4 c0 = *(const float4*)&basek[32 * s + 8 * lg];
                const float4 c4 = *(const float4*)&basek[32 * s + 8 * lg + 4];
                uint4 hv;
                hv.x = cvt2(fmaxf(a0.x + c0.x, 0.f), fmaxf(a0.y + c0.y, 0.f));
                hv.y = cvt2(fmaxf(a0.z + c0.z, 0.f), fmaxf(a0.w + c0.w, 0.f));
                hv.z = cvt2(fmaxf(a1.x + c4.x, 0.f), fmaxf(a1.y + c4.y, 0.f));
                hv.w = cvt2(fmaxf(a1.z + c4.z, 0.f), fmaxf(a1.w + c4.w, 0.f));
                *(uint4*)&h1f[((mtA * 8 + s) * 64 + l) * 8] = hv;
            }
        }
        // W2 B-fragments for this wave's n-slice (per-tile lifetime, dies at B end)
        s16x8 bfr[32];
#pragma unroll
        for (int s = 0; s < 8; ++s)
#pragma unroll
            for (int n = 0; n < 4; ++n)
                bfr[s * 4 + n] = *(const s16x8*)(w2fg +
                    (size_t)(((s * 16 + 4 * w + n) * 64 + l)) * 8);
        BAR_LDS();   // bar1: h1f ready

        // ---- phase B: mt-outer (2 blocks); acc bias-seeded; 64 MFMA/wave
#pragma unroll
        for (int mt = 0; mt < 2; ++mt) {
            s16x8 a[8];
#pragma unroll
            for (int s = 0; s < 8; ++s)
                a[s] = *(const s16x8*)&h1f[((mt * 8 + s) * 64 + l) * 8];
#pragma unroll
            for (int n = 0; n < 4; ++n) {
                f32x4 acc = {bias[n], bias[n], bias[n], bias[n]};
#pragma unroll
                for (int s = 0; s < 8; ++s)
                    acc = __builtin_amdgcn_mfma_f32_16x16x32_bf16(a[s], bfr[s * 4 + n], acc, 0, 0, 0);
                const int col = 64 * w + 16 * n + l15;
                const int jrow = 16 * mt + 4 * lg;
#pragma unroll
                for (int r = 0; r < 4; ++r)
                    h2s[(jrow + r) * 264 + col] = (short)bf_bits(fmaxf(acc[r], 0.f));
            }
        }
        BAR_LDS();   // bar2: h2s ready

        // ---- phase C (waves 0-1): score2 = H2 @ w3q; combine with fp32 S1
        if (w < 2) {
            float4 s1v = make_float4(0.f, 0.f, 0.f, 0.f);
            if (l15 < 8)
                s1v = *(const float4*)(S1 + (size_t)l15 * (N * N) + (size_t)i * N
                                       + j0 + 16 * w + 4 * lg);
            f32x4 acc2 = {};
#pragma unroll
            for (int s = 0; s < 8; ++s) {
                const s16x8 a2 = *(const s16x8*)&h2s[(16 * w + l15) * 264 + 32 * s + 8 * lg];
                const s16x8 wq = *(const s16x8*)&w3qf[(s * 64 + l) * 8];
                acc2 = __builtin_amdgcn_mfma_f32_16x16x32_bf16(a2, wq, acc2, 0, 0, 0);
            }
            if (l15 < 8) {
                float4 sc;
                sc.x = (acc2[0] + s1v.x) * SCALE_INV;
                sc.y = (acc2[1] + s1v.y) * SCALE_INV;
                sc.z = (acc2[2] + s1v.z) * SCALE_INV;
                sc.w = (acc2[3] + s1v.w) * SCALE_INV;
                *(float4*)&slds[l15 * 36 + 16 * w + 4 * lg] = sc;
            }
        }
        BAR_LDS();   // bar3: slds scores ready

        // ---- p-gen: half-wave; lanes<32 -> head w, lanes>=32 -> head w+4
        {
            const int hpg = w + ((l >> 5) << 2);
            const int col = l & 31;
            const float sc = slds[hpg * 36 + col];
            float m0 = sc;
#pragma unroll
            for (int o = 1; o < 32; o <<= 1) m0 = fmaxf(m0, __shfl_xor(m0, o));
            const float M0 = hm[hpg];
            const float nm = fmaxf(M0, m0);
            const float p = __expf(sc - nm);
            plds[hpg * 36 + col] = p;
            float ts = p;
#pragma unroll
            for (int o = 1; o < 32; o <<= 1) ts += __shfl_xor(ts, o);
            if (col == 0) {
                const float r = __expf(M0 - nm);
                hresc[hpg] = r;
                hpsum[hpg] = hpsum[hpg] * r + ts;
                hm[hpg] = nm;
            }
        }
        BAR_LDS();   // bar4: plds + per-head state ready

        // ---- phase D: PV accumulate (p from LDS broadcast, V bf16 from L2)
        {
            pv *= hresc[h];
            const unsigned short* vp = vrow + j0;
            const float* pp = &plds[h * 36];
#pragma unroll
            for (int c = 0; c < 4; ++c) {
                const s16x8 vv = *(const s16x8*)(vp + c * 8);
                const float4 pa = *(const float4*)(pp + 8 * c);
                const float4 pb = *(const float4*)(pp + 8 * c + 4);
                pv += pa.x * bf2f((unsigned short)vv[0]) + pa.y * bf2f((unsigned short)vv[1])
                    + pa.z * bf2f((unsigned short)vv[2]) + pa.w * bf2f((unsigned short)vv[3])
                    + pb.x * bf2f((unsigned short)vv[4]) + pb.y * bf2f((unsigned short)vv[5])
                    + pb.z * bf2f((unsigned short)vv[6]) + pb.w * bf2f((unsigned short)vv[7]);
            }
        }
        // no end-of-tile barrier: plds/hresc rewrite (p-gen t+1) is 3 barriers
        // away; h1f rewrite (phase A t+1) conflicts only with B reads (pre-bar2)
    }

    // ---------------- epilogue: normalize + WoT projection (oa overlays slds)
    const float ov = pv / hpsum[h];
    BAR_LDS();       // all p-gen reads of slds done before overlay
    oa[t] = ov;
    BAR_LDS();
    float r = bo[t];
    const float* wop = WoT + (size_t)t * HID;
#pragma unroll 4
    for (int k = 0; k < HID; k += 4) {
        const float4 o4 = *(const float4*)&oa[k];
        const float4 wv = *(const float4*)(wop + k);
        r += o4.x * wv.x + o4.y * wv.y + o4.z * wv.z + o4.w * wv.w;
    }
    out[(size_t)i * HID + t] = r;
}

// ---------------------------------------------------------------------------
extern "C" void kernel_launch(void* const* d_in, const int* in_sizes, int n_in,
                              void* d_out, int out_size, void* d_ws, size_t ws_size,
                              hipStream_t stream)
{
    const float* x   = (const float*)d_in[0];
    const float* pos = (const float*)d_in[1];
    const float* Wq  = (const float*)d_in[2];
    const float* bq  = (const float*)d_in[3];
    const float* Wk  = (const float*)d_in[4];
    const float* bk  = (const float*)d_in[5];
    const float* Wv  = (const float*)d_in[6];
    const float* bv  = (const float*)d_in[7];
    const float* Wo  = (const float*)d_in[8];
    const float* bo  = (const float*)d_in[9];
    const float* W1  = (const float*)d_in[10];
    const float* b1  = (const float*)d_in[11];
    const float* W2  = (const float*)d_in[12];
    const float* b2  = (const float*)d_in[13];
    const float* W3  = (const float*)d_in[14];
    const float* b3  = (const float*)d_in[15];  // softmax-invariant, folded out
    (void)b3;
    float* out = (float*)d_out;

    char* ws = (char*)d_ws;
    float* Q  = (float*)(ws + 0);                            // 768*256 f32
    float* A  = (float*)(ws + 786432);                       // 768*256 f32
    float* Kt = (float*)(ws + 1572864);                      // 256*768 f32
    unsigned short* Vtb = (unsigned short*)(ws + 2359296);   // 256*768 bf16
    float* S1 = (float*)(ws + 2752512);                      // 8*768*768 f32
    unsigned short* w2f  = (unsigned short*)(ws + 21626880); // 65536 bf16
    unsigned short* w3qg = (unsigned short*)(ws + 21757952); // 768*4096 bf16
    float* WoT = (float*)(ws + 28049408);                    // 256*256 f32

    prep_kernel<<<1024, 256, 0, stream>>>(x, pos, Wq, bq, Wk, bk, Wv, bv,
                                          W1, W2, W3, Wo,
                                          Q, Kt, Vtb, A, w2f, WoT, w3qg);
    s1_kernel<<<288, 256, 0, stream>>>(Q, Kt, S1);
    fused_main_kernel<<<N, 256, 0, stream>>>(A, S1, Vtb, w2f, w3qg,
                                             b1, b2, WoT, bo, out);
}

// Round 15
// 230.751 us; speedup vs baseline: 1.1454x; 1.1454x over previous
//
#include <hip/hip_runtime.h>
#include <hip/hip_bf16.h>

#define N 768
#define IN_DIM 128
#define HID 256
#define HD 32
#define TJ 64
#define NT (N / TJ)
#define SCALE_INV 0.17677669529663687f  // 1/sqrt(32)

typedef short s16x8 __attribute__((ext_vector_type(8)));
typedef float f32x4 __attribute__((ext_vector_type(4)));

__device__ __forceinline__ float bf2f(unsigned short s) {
    return __uint_as_float(((unsigned)s) << 16);
}
__device__ __forceinline__ unsigned short bf_bits(float f) {
    __hip_bfloat16 h = __float2bfloat16(f);
    union { __hip_bfloat16 h; unsigned short u; } c; c.h = h; return c.u;
}
__device__ __forceinline__ unsigned cvt2(float a, float b) {
    __hip_bfloat162 h2 = __float22bfloat162_rn(make_float2(a, b));
    union { __hip_bfloat162 h; unsigned u; } c; c.h = h2; return c.u;
}

// LDS-only barrier: waits own-wave LDS ops, leaves global loads in flight.
#define BAR_LDS() do { asm volatile("s_waitcnt lgkmcnt(0)" ::: "memory"); \
                       __builtin_amdgcn_s_barrier(); } while (0)

// ---------------------------------------------------------------------------
// kernel 1 (grid 1024):
//  blocks 0..767   : per-i prep -> Q f32; Kt = K^T f32; Vt = V^T bf16;
//                    A = pos@W1 f32; w3q fragments for row i
//  blocks 768..1023: pack W2 into MFMA B-frag order + transpose Wo
// ---------------------------------------------------------------------------
__global__ __launch_bounds__(256) void prep_kernel(
    const float* __restrict__ x, const float* __restrict__ pos,
    const float* __restrict__ Wq, const float* __restrict__ bq,
    const float* __restrict__ Wk, const float* __restrict__ bk,
    const float* __restrict__ Wv, const float* __restrict__ bv,
    const float* __restrict__ W1, const float* __restrict__ W2,
    const float* __restrict__ W3, const float* __restrict__ Wo,
    float* __restrict__ Q, float* __restrict__ Kt,
    unsigned short* __restrict__ Vt, float* __restrict__ A,
    unsigned short* __restrict__ w2f, float* __restrict__ WoT,
    unsigned short* __restrict__ w3qg)
{
    const int bx = blockIdx.x, t = threadIdx.x;
    __shared__ float xs[IN_DIM];
    __shared__ float ps[3];
    __shared__ float qrow[HID];

    if (bx >= N) {
        // pack W2 B-frags: w2f[((s*16+nt)*64+l)*8+e] = W2[32s+8(l>>4)+e][16nt+(l&15)]
        const int p = (bx - N) * 256 + t;               // 0..65535
        const int e = p & 7, l = (p >> 3) & 63, nt = (p >> 9) & 15, s = p >> 13;
        const int krow = 32 * s + 8 * (l >> 4) + e;     // contraction index
        const int ncol = 16 * nt + (l & 15);            // output n index
        w2f[p] = bf_bits(W2[krow * HID + ncol]);
        WoT[p] = Wo[(p & 255) * HID + (p >> 8)];        // WoT[t][k] = Wo[k][t]
        return;
    }

    const int i = bx;
    if (t < IN_DIM) xs[t] = x[i * IN_DIM + t];
    if (t < 3) ps[t] = pos[i * 3 + t];
    __syncthreads();
    float q = bq[t], k = bk[t], v = bv[t];
#pragma unroll 8
    for (int kk = 0; kk < IN_DIM; ++kk) {
        const float xv = xs[kk];
        q += xv * Wq[kk * HID + t];
        k += xv * Wk[kk * HID + t];
        v += xv * Wv[kk * HID + t];
    }
    const float a = ps[0] * W1[t] + ps[1] * W1[HID + t] + ps[2] * W1[2 * HID + t];
    Q[i * HID + t] = q;
    Kt[(size_t)t * N + i] = k;
    Vt[(size_t)t * N + i] = bf_bits(v);
    A[i * HID + t] = a;
    qrow[t] = q;
    __syncthreads();

    // w3q frags: w3q[h][k] = sum_d W3[k][d]*q[h*32+d], B-frag order
    const int l = t & 63, sp = t >> 6, lg = l >> 4, hh = l & 15;
#pragma unroll
    for (int ss = 0; ss < 2; ++ss) {
        const int s = 2 * sp + ss;
        s16x8 frag = {0, 0, 0, 0, 0, 0, 0, 0};
        if (hh < 8) {
#pragma unroll
            for (int e = 0; e < 8; ++e) {
                const int kk = 32 * s + 8 * lg + e;
                const float* w3p = W3 + kk * HD;
                float acc = 0.f;
#pragma unroll
                for (int d0 = 0; d0 < 32; d0 += 4) {
                    const float4 wv = *(const float4*)(w3p + d0);
                    acc += wv.x * qrow[hh * HD + d0] + wv.y * qrow[hh * HD + d0 + 1]
                         + wv.z * qrow[hh * HD + d0 + 2] + wv.w * qrow[hh * HD + d0 + 3];
                }
                frag[e] = (short)bf_bits(acc);
            }
        }
        *(s16x8*)(w3qg + (size_t)i * 4096 + (size_t)(s * 64 + l) * 8) = frag;
    }
}

// ---------------------------------------------------------------------------
// kernel 2: S1[h][i][j] = q_i,h . k_j,h (f32). 32 i x 64 j x 8 h per block.
// ---------------------------------------------------------------------------
__global__ __launch_bounds__(256) void s1_kernel(
    const float* __restrict__ Q, const float* __restrict__ Kt,
    float* __restrict__ S1)
{
    const int t = threadIdx.x;
    const int i0 = (blockIdx.x / 12) * 32;
    const int j0 = (blockIdx.x % 12) * 64;
    __shared__ float qTs[256 * 36];   // [d'][i], row stride 36, XOR-swizzled chunks

    {
        const int iq = t & 31;
        const int dbase = (t >> 5) * 32;
        const int xk = t >> 5;
        const int colsw = (((iq >> 2) ^ xk) << 2) + (iq & 3);
        const float* qp = Q + (size_t)(i0 + iq) * HID + dbase;
#pragma unroll
        for (int cc = 0; cc < 8; ++cc) {
            const float4 qv = *(const float4*)(qp + 4 * cc);
            qTs[(dbase + 4 * cc + 0) * 36 + colsw] = qv.x;
            qTs[(dbase + 4 * cc + 1) * 36 + colsw] = qv.y;
            qTs[(dbase + 4 * cc + 2) * 36 + colsw] = qv.z;
            qTs[(dbase + 4 * cc + 3) * 36 + colsw] = qv.w;
        }
    }
    __syncthreads();

    const int h = t >> 5, jj = t & 31;
    const int j1 = j0 + jj, j2 = j0 + jj + 32;
    f32x4 acc0[8] = {}, acc1[8] = {};
    const float* kp = Kt + (size_t)(32 * h) * N + j1;
#pragma unroll 4
    for (int d = 0; d < 32; ++d) {
        const float k0 = kp[(size_t)d * N];
        const float k1 = kp[(size_t)d * N + 32];
        const float* qrow = &qTs[(32 * h + d) * 36];
#pragma unroll
        for (int ic = 0; ic < 8; ++ic) {
            const f32x4 qv = *(const f32x4*)&qrow[(ic ^ h) << 2];
            acc0[ic] += qv * k0;
            acc1[ic] += qv * k1;
        }
    }
    float* op = S1 + (size_t)h * (N * N) + (size_t)i0 * N;
#pragma unroll
    for (int ic = 0; ic < 8; ++ic)
#pragma unroll
        for (int u = 0; u < 4; ++u) {
            op[(size_t)(4 * ic + u) * N + j1] = acc0[ic][u];
            op[(size_t)(4 * ic + u) * N + j2] = acc1[ic][u];
        }
}

// ---------------------------------------------------------------------------
// kernel 3: fused main — r13 structure (measured 201.5 us) + s_setprio(1)
// around MFMA clusters (T5: pays when independent blocks co-reside at
// different phases — 2 blocks/CU here). 4 waves/block, 4 LDS-only
// barriers/tile. Phase B: mt-outer, bfr[32] dies at B end.
// ---------------------------------------------------------------------------
__global__ __launch_bounds__(256, 2) void fused_main_kernel(
    const float* __restrict__ Ag, const float* __restrict__ S1,
    const unsigned short* __restrict__ Vt,
    const unsigned short* __restrict__ w2fg, const unsigned short* __restrict__ w3qg,
    const float* __restrict__ b1, const float* __restrict__ b2,
    const float* __restrict__ WoT, const float* __restrict__ bo,
    float* __restrict__ out)
{
    const int i = blockIdx.x, t = threadIdx.x;
    const int w = t >> 6, l = t & 63;
    const int lg = l >> 4, l15 = l & 15;

    __shared__ __align__(16) short h1f[4 * 8 * 64 * 8];   // 32 KB  H1 A-frags
    __shared__ __align__(16) short h2s[64 * 264];          // 33 KB  H2 [j][k]
    __shared__ __align__(16) short w3qf[8 * 64 * 8];       // 8 KB   w3q B-frags
    __shared__ __align__(16) float slds[8 * 68];           // scores [h][jj]
    __shared__ __align__(16) float plds[8 * 68];           // probs  [h][jj]
    __shared__ float basek[HID];
    __shared__ float oa[HID];
    __shared__ float hm[8], hpsum[8], hresc[8];

    // ---------------- prolog
    basek[t] = b1[t] - Ag[(size_t)i * HID + t];
    {
        const int c0 = t, c1 = t + 256;
        *(s16x8*)&w3qf[c0 * 8] = *(const s16x8*)(w3qg + (size_t)i * 4096 + (size_t)c0 * 8);
        *(s16x8*)&w3qf[c1 * 8] = *(const s16x8*)(w3qg + (size_t)i * 4096 + (size_t)c1 * 8);
    }
    if (t < 8) { hm[t] = -3.0e38f; hpsum[t] = 0.f; }
    float bias[4];
#pragma unroll
    for (int n = 0; n < 4; ++n) bias[n] = b2[64 * w + 16 * n + l15];

    float pv = 0.f;
    const int h = t >> 5;
    const unsigned short* vrow = Vt + (size_t)t * N;
    BAR_LDS();

#pragma unroll 1
    for (int tile = 0; tile < NT; ++tile) {
        const int j0 = tile * TJ;

        // ---- phase A: H1 = relu(A[j] - A[i] + b1) in A-fragment order
        const int jj = 16 * w + l15;
        const float* ap = Ag + (size_t)(j0 + jj) * HID + 8 * lg;
#pragma unroll
        for (int s = 0; s < 8; ++s) {
            const float4 a0 = *(const float4*)(ap + 32 * s);
            const float4 a1 = *(const float4*)(ap + 32 * s + 4);
            const float4 c0 = *(const float4*)&basek[32 * s + 8 * lg];
            const float4 c4 = *(const float4*)&basek[32 * s + 8 * lg + 4];
            uint4 hv;
            hv.x = cvt2(fmaxf(a0.x + c0.x, 0.f), fmaxf(a0.y + c0.y, 0.f));
            hv.y = cvt2(fmaxf(a0.z + c0.z, 0.f), fmaxf(a0.w + c0.w, 0.f));
            hv.z = cvt2(fmaxf(a1.x + c4.x, 0.f), fmaxf(a1.y + c4.y, 0.f));
            hv.w = cvt2(fmaxf(a1.z + c4.z, 0.f), fmaxf(a1.w + c4.w, 0.f));
            *(uint4*)&h1f[((w * 8 + s) * 64 + l) * 8] = hv;
        }
        // W2 B-fragments for this wave's n-slice (per-tile lifetime, dies at B end)
        s16x8 bfr[32];
#pragma unroll
        for (int s = 0; s < 8; ++s)
#pragma unroll
            for (int n = 0; n < 4; ++n)
                bfr[s * 4 + n] = *(const s16x8*)(w2fg +
                    (size_t)(((s * 16 + 4 * w + n) * 64 + l)) * 8);
        BAR_LDS();   // bar1: h1f ready

        // ---- phase B: mt-outer; acc bias-seeded; 128 MFMA/wave
        __builtin_amdgcn_s_setprio(1);
#pragma unroll
        for (int mt = 0; mt < 4; ++mt) {
            s16x8 a[8];
#pragma unroll
            for (int s = 0; s < 8; ++s)
                a[s] = *(const s16x8*)&h1f[((mt * 8 + s) * 64 + l) * 8];
#pragma unroll
            for (int n = 0; n < 4; ++n) {
                f32x4 acc = {bias[n], bias[n], bias[n], bias[n]};
#pragma unroll
                for (int s = 0; s < 8; ++s)
                    acc = __builtin_amdgcn_mfma_f32_16x16x32_bf16(a[s], bfr[s * 4 + n], acc, 0, 0, 0);
                const int col = 64 * w + 16 * n + l15;
                const int jrow = 16 * mt + 4 * lg;
#pragma unroll
                for (int r = 0; r < 4; ++r)
                    h2s[(jrow + r) * 264 + col] = (short)bf_bits(fmaxf(acc[r], 0.f));
            }
        }
        __builtin_amdgcn_s_setprio(0);
        BAR_LDS();   // bar2: h2s ready

        // ---- phase C: score2 = H2 @ w3q; combine with fp32 S1
        float4 s1v = make_float4(0.f, 0.f, 0.f, 0.f);
        if (l15 < 8)
            s1v = *(const float4*)(S1 + (size_t)l15 * (N * N) + (size_t)i * N
                                   + j0 + 16 * w + 4 * lg);
        f32x4 acc2 = {};
        __builtin_amdgcn_s_setprio(1);
#pragma unroll
        for (int s = 0; s < 8; ++s) {
            const s16x8 a2 = *(const s16x8*)&h2s[(16 * w + l15) * 264 + 32 * s + 8 * lg];
            const s16x8 wq = *(const s16x8*)&w3qf[(s * 64 + l) * 8];
            acc2 = __builtin_amdgcn_mfma_f32_16x16x32_bf16(a2, wq, acc2, 0, 0, 0);
        }
        __builtin_amdgcn_s_setprio(0);
        if (l15 < 8) {
            float4 sc;
            sc.x = (acc2[0] + s1v.x) * SCALE_INV;
            sc.y = (acc2[1] + s1v.y) * SCALE_INV;
            sc.z = (acc2[2] + s1v.z) * SCALE_INV;
            sc.w = (acc2[3] + s1v.w) * SCALE_INV;
            *(float4*)&slds[l15 * 68 + 16 * w + 4 * lg] = sc;
        }
        BAR_LDS();   // bar3: slds scores ready

        // ---- p-gen: wave w owns heads {w, w+4}; 2 exps/thread
        {
            const int h0 = w, h1 = w + 4;
            const float s0 = slds[h0 * 68 + l];
            const float s1 = slds[h1 * 68 + l];
            float m0 = s0, m1 = s1;
#pragma unroll
            for (int o = 1; o < 64; o <<= 1) {
                m0 = fmaxf(m0, __shfl_xor(m0, o));
                m1 = fmaxf(m1, __shfl_xor(m1, o));
            }
            const float M0 = hm[h0], M1 = hm[h1];
            const float nm0 = fmaxf(M0, m0), nm1 = fmaxf(M1, m1);
            const float p0 = __expf(s0 - nm0), p1 = __expf(s1 - nm1);
            plds[h0 * 68 + l] = p0;
            plds[h1 * 68 + l] = p1;
            float t0 = p0, t1 = p1;
#pragma unroll
            for (int o = 1; o < 64; o <<= 1) {
                t0 += __shfl_xor(t0, o);
                t1 += __shfl_xor(t1, o);
            }
            if (l == 0) {
                const float r0 = __expf(M0 - nm0), r1 = __expf(M1 - nm1);
                hresc[h0] = r0; hresc[h1] = r1;
                hpsum[h0] = hpsum[h0] * r0 + t0;
                hpsum[h1] = hpsum[h1] * r1 + t1;
                hm[h0] = nm0; hm[h1] = nm1;
            }
        }
        BAR_LDS();   // bar4: plds + per-head state ready

        // ---- phase D: PV accumulate (p from LDS broadcast, V bf16 from L2)
        {
            pv *= hresc[h];
            const unsigned short* vp = vrow + j0;
            const float* pp = &plds[h * 68];
#pragma unroll
            for (int c = 0; c < 8; ++c) {
                const s16x8 vv = *(const s16x8*)(vp + c * 8);
                const float4 pa = *(const float4*)(pp + 8 * c);
                const float4 pb = *(const float4*)(pp + 8 * c + 4);
                pv += pa.x * bf2f((unsigned short)vv[0]) + pa.y * bf2f((unsigned short)vv[1])
                    + pa.z * bf2f((unsigned short)vv[2]) + pa.w * bf2f((unsigned short)vv[3])
                    + pb.x * bf2f((unsigned short)vv[4]) + pb.y * bf2f((unsigned short)vv[5])
                    + pb.z * bf2f((unsigned short)vv[6]) + pb.w * bf2f((unsigned short)vv[7]);
            }
        }
        // no end-of-tile barrier: plds/hresc rewrite (p-gen t+1) is 3 barriers
        // away; h1f rewrite (phase A t+1) conflicts only with B reads (pre-bar2)
    }

    // ---------------- epilogue: normalize + WoT projection
    oa[t] = pv / hpsum[h];
    BAR_LDS();
    float r = bo[t];
    const float* wop = WoT + (size_t)t * HID;
#pragma unroll 4
    for (int k = 0; k < HID; k += 4) {
        const float4 ov = *(const float4*)&oa[k];
        const float4 wv = *(const float4*)(wop + k);
        r += ov.x * wv.x + ov.y * wv.y + ov.z * wv.z + ov.w * wv.w;
    }
    out[(size_t)i * HID + t] = r;
}

// ---------------------------------------------------------------------------
extern "C" void kernel_launch(void* const* d_in, const int* in_sizes, int n_in,
                              void* d_out, int out_size, void* d_ws, size_t ws_size,
                              hipStream_t stream)
{
    const float* x   = (const float*)d_in[0];
    const float* pos = (const float*)d_in[1];
    const float* Wq  = (const float*)d_in[2];
    const float* bq  = (const float*)d_in[3];
    const float* Wk  = (const float*)d_in[4];
    const float* bk  = (const float*)d_in[5];
    const float* Wv  = (const float*)d_in[6];
    const float* bv  = (const float*)d_in[7];
    const float* Wo  = (const float*)d_in[8];
    const float* bo  = (const float*)d_in[9];
    const float* W1  = (const float*)d_in[10];
    const float* b1  = (const float*)d_in[11];
    const float* W2  = (const float*)d_in[12];
    const float* b2  = (const float*)d_in[13];
    const float* W3  = (const float*)d_in[14];
    const float* b3  = (const float*)d_in[15];  // softmax-invariant, folded out
    (void)b3;
    float* out = (float*)d_out;

    char* ws = (char*)d_ws;
    float* Q  = (float*)(ws + 0);                            // 768*256 f32
    float* A  = (float*)(ws + 786432);                       // 768*256 f32
    float* Kt = (float*)(ws + 1572864);                      // 256*768 f32
    unsigned short* Vtb = (unsigned short*)(ws + 2359296);   // 256*768 bf16
    float* S1 = (float*)(ws + 2752512);                      // 8*768*768 f32
    unsigned short* w2f  = (unsigned short*)(ws + 21626880); // 65536 bf16
    unsigned short* w3qg = (unsigned short*)(ws + 21757952); // 768*4096 bf16
    float* WoT = (float*)(ws + 28049408);                    // 256*256 f32

    prep_kernel<<<1024, 256, 0, stream>>>(x, pos, Wq, bq, Wk, bk, Wv, bv,
                                          W1, W2, W3, Wo,
                                          Q, Kt, Vtb, A, w2f, WoT, w3qg);
    s1_kernel<<<288, 256, 0, stream>>>(Q, Kt, S1);
    fused_main_kernel<<<N, 256, 0, stream>>>(A, S1, Vtb, w2f, w3qg,
                                             b1, b2, WoT, bo, out);
}

// Round 16
// 227.862 us; speedup vs baseline: 1.1600x; 1.0127x over previous
//
#include <hip/hip_runtime.h>
#include <hip/hip_bf16.h>

#define N 768
#define IN_DIM 128
#define HID 256
#define HD 32
#define TJ 64
#define NT (N / TJ)
#define SCALE_INV 0.17677669529663687f  // 1/sqrt(32)

typedef short s16x8 __attribute__((ext_vector_type(8)));
typedef float f32x4 __attribute__((ext_vector_type(4)));

__device__ __forceinline__ float bf2f(unsigned short s) {
    return __uint_as_float(((unsigned)s) << 16);
}
__device__ __forceinline__ unsigned short bf_bits(float f) {
    __hip_bfloat16 h = __float2bfloat16(f);
    union { __hip_bfloat16 h; unsigned short u; } c; c.h = h; return c.u;
}
__device__ __forceinline__ unsigned cvt2(float a, float b) {
    __hip_bfloat162 h2 = __float22bfloat162_rn(make_float2(a, b));
    union { __hip_bfloat162 h; unsigned u; } c; c.h = h2; return c.u;
}

// LDS-only barrier: waits own-wave LDS ops, leaves global loads in flight.
#define BAR_LDS() do { asm volatile("s_waitcnt lgkmcnt(0)" ::: "memory"); \
                       __builtin_amdgcn_s_barrier(); } while (0)

// ---------------------------------------------------------------------------
// kernel 1 (grid 1024):
//  blocks 0..767   : per-i prep -> Q f32; Kt = K^T f32; Vt = V^T bf16;
//                    A = pos@W1 f32; w3q fragments for row i
//  blocks 768..1023: pack W2 into MFMA B-frag order + transpose Wo
// ---------------------------------------------------------------------------
__global__ __launch_bounds__(256) void prep_kernel(
    const float* __restrict__ x, const float* __restrict__ pos,
    const float* __restrict__ Wq, const float* __restrict__ bq,
    const float* __restrict__ Wk, const float* __restrict__ bk,
    const float* __restrict__ Wv, const float* __restrict__ bv,
    const float* __restrict__ W1, const float* __restrict__ W2,
    const float* __restrict__ W3, const float* __restrict__ Wo,
    float* __restrict__ Q, float* __restrict__ Kt,
    unsigned short* __restrict__ Vt, float* __restrict__ A,
    unsigned short* __restrict__ w2f, float* __restrict__ WoT,
    unsigned short* __restrict__ w3qg)
{
    const int bx = blockIdx.x, t = threadIdx.x;
    __shared__ float xs[IN_DIM];
    __shared__ float ps[3];
    __shared__ float qrow[HID];

    if (bx >= N) {
        // pack W2 B-frags: w2f[((s*16+nt)*64+l)*8+e] = W2[32s+8(l>>4)+e][16nt+(l&15)]
        const int p = (bx - N) * 256 + t;               // 0..65535
        const int e = p & 7, l = (p >> 3) & 63, nt = (p >> 9) & 15, s = p >> 13;
        const int krow = 32 * s + 8 * (l >> 4) + e;     // contraction index
        const int ncol = 16 * nt + (l & 15);            // output n index
        w2f[p] = bf_bits(W2[krow * HID + ncol]);
        WoT[p] = Wo[(p & 255) * HID + (p >> 8)];        // WoT[t][k] = Wo[k][t]
        return;
    }

    const int i = bx;
    if (t < IN_DIM) xs[t] = x[i * IN_DIM + t];
    if (t < 3) ps[t] = pos[i * 3 + t];
    __syncthreads();
    float q = bq[t], k = bk[t], v = bv[t];
#pragma unroll 8
    for (int kk = 0; kk < IN_DIM; ++kk) {
        const float xv = xs[kk];
        q += xv * Wq[kk * HID + t];
        k += xv * Wk[kk * HID + t];
        v += xv * Wv[kk * HID + t];
    }
    const float a = ps[0] * W1[t] + ps[1] * W1[HID + t] + ps[2] * W1[2 * HID + t];
    Q[i * HID + t] = q;
    Kt[(size_t)t * N + i] = k;
    Vt[(size_t)t * N + i] = bf_bits(v);
    A[i * HID + t] = a;
    qrow[t] = q;
    __syncthreads();

    // w3q frags: w3q[h][k] = sum_d W3[k][d]*q[h*32+d], B-frag order
    const int l = t & 63, sp = t >> 6, lg = l >> 4, hh = l & 15;
#pragma unroll
    for (int ss = 0; ss < 2; ++ss) {
        const int s = 2 * sp + ss;
        s16x8 frag = {0, 0, 0, 0, 0, 0, 0, 0};
        if (hh < 8) {
#pragma unroll
            for (int e = 0; e < 8; ++e) {
                const int kk = 32 * s + 8 * lg + e;
                const float* w3p = W3 + kk * HD;
                float acc = 0.f;
#pragma unroll
                for (int d0 = 0; d0 < 32; d0 += 4) {
                    const float4 wv = *(const float4*)(w3p + d0);
                    acc += wv.x * qrow[hh * HD + d0] + wv.y * qrow[hh * HD + d0 + 1]
                         + wv.z * qrow[hh * HD + d0 + 2] + wv.w * qrow[hh * HD + d0 + 3];
                }
                frag[e] = (short)bf_bits(acc);
            }
        }
        *(s16x8*)(w3qg + (size_t)i * 4096 + (size_t)(s * 64 + l) * 8) = frag;
    }
}

// ---------------------------------------------------------------------------
// kernel 2: S1[h][i][j] = q_i,h . k_j,h (f32). 32 i x 64 j x 8 h per block.
// ---------------------------------------------------------------------------
__global__ __launch_bounds__(256) void s1_kernel(
    const float* __restrict__ Q, const float* __restrict__ Kt,
    float* __restrict__ S1)
{
    const int t = threadIdx.x;
    const int i0 = (blockIdx.x / 12) * 32;
    const int j0 = (blockIdx.x % 12) * 64;
    __shared__ float qTs[256 * 36];   // [d'][i], row stride 36, XOR-swizzled chunks

    {
        const int iq = t & 31;
        const int dbase = (t >> 5) * 32;
        const int xk = t >> 5;
        const int colsw = (((iq >> 2) ^ xk) << 2) + (iq & 3);
        const float* qp = Q + (size_t)(i0 + iq) * HID + dbase;
#pragma unroll
        for (int cc = 0; cc < 8; ++cc) {
            const float4 qv = *(const float4*)(qp + 4 * cc);
            qTs[(dbase + 4 * cc + 0) * 36 + colsw] = qv.x;
            qTs[(dbase + 4 * cc + 1) * 36 + colsw] = qv.y;
            qTs[(dbase + 4 * cc + 2) * 36 + colsw] = qv.z;
            qTs[(dbase + 4 * cc + 3) * 36 + colsw] = qv.w;
        }
    }
    __syncthreads();

    const int h = t >> 5, jj = t & 31;
    const int j1 = j0 + jj, j2 = j0 + jj + 32;
    f32x4 acc0[8] = {}, acc1[8] = {};
    const float* kp = Kt + (size_t)(32 * h) * N + j1;
#pragma unroll 4
    for (int d = 0; d < 32; ++d) {
        const float k0 = kp[(size_t)d * N];
        const float k1 = kp[(size_t)d * N + 32];
        const float* qrow = &qTs[(32 * h + d) * 36];
#pragma unroll
        for (int ic = 0; ic < 8; ++ic) {
            const f32x4 qv = *(const f32x4*)&qrow[(ic ^ h) << 2];
            acc0[ic] += qv * k0;
            acc1[ic] += qv * k1;
        }
    }
    float* op = S1 + (size_t)h * (N * N) + (size_t)i0 * N;
#pragma unroll
    for (int ic = 0; ic < 8; ++ic)
#pragma unroll
        for (int u = 0; u < 4; ++u) {
            op[(size_t)(4 * ic + u) * N + j1] = acc0[ic][u];
            op[(size_t)(4 * ic + u) * N + j2] = acc1[ic][u];
        }
}

// ---------------------------------------------------------------------------
// kernel 3: fused main — final configuration (r13, measured 201.5 us main /
// 227.6 us total). 4 waves/block, 2 blocks/CU, 4 LDS-only barriers/tile.
// Phase B: mt-outer, H1 as A-operand, W2 B-frags in bfr[32] (per-tile
// lifetime, dies at end of B — spill-free). p-gen: wave w owns heads
// {w, w+4}; PV head = t>>5 with LDS hresc/hpsum state.
// ---------------------------------------------------------------------------
__global__ __launch_bounds__(256, 2) void fused_main_kernel(
    const float* __restrict__ Ag, const float* __restrict__ S1,
    const unsigned short* __restrict__ Vt,
    const unsigned short* __restrict__ w2fg, const unsigned short* __restrict__ w3qg,
    const float* __restrict__ b1, const float* __restrict__ b2,
    const float* __restrict__ WoT, const float* __restrict__ bo,
    float* __restrict__ out)
{
    const int i = blockIdx.x, t = threadIdx.x;
    const int w = t >> 6, l = t & 63;
    const int lg = l >> 4, l15 = l & 15;

    __shared__ __align__(16) short h1f[4 * 8 * 64 * 8];   // 32 KB  H1 A-frags
    __shared__ __align__(16) short h2s[64 * 264];          // 33 KB  H2 [j][k]
    __shared__ __align__(16) short w3qf[8 * 64 * 8];       // 8 KB   w3q B-frags
    __shared__ __align__(16) float slds[8 * 68];           // scores [h][jj]
    __shared__ __align__(16) float plds[8 * 68];           // probs  [h][jj]
    __shared__ float basek[HID];
    __shared__ float oa[HID];
    __shared__ float hm[8], hpsum[8], hresc[8];

    // ---------------- prolog
    basek[t] = b1[t] - Ag[(size_t)i * HID + t];
    {
        const int c0 = t, c1 = t + 256;
        *(s16x8*)&w3qf[c0 * 8] = *(const s16x8*)(w3qg + (size_t)i * 4096 + (size_t)c0 * 8);
        *(s16x8*)&w3qf[c1 * 8] = *(const s16x8*)(w3qg + (size_t)i * 4096 + (size_t)c1 * 8);
    }
    if (t < 8) { hm[t] = -3.0e38f; hpsum[t] = 0.f; }
    float bias[4];
#pragma unroll
    for (int n = 0; n < 4; ++n) bias[n] = b2[64 * w + 16 * n + l15];

    float pv = 0.f;
    const int h = t >> 5;
    const unsigned short* vrow = Vt + (size_t)t * N;
    BAR_LDS();

#pragma unroll 1
    for (int tile = 0; tile < NT; ++tile) {
        const int j0 = tile * TJ;

        // ---- phase A: H1 = relu(A[j] - A[i] + b1) in A-fragment order
        const int jj = 16 * w + l15;
        const float* ap = Ag + (size_t)(j0 + jj) * HID + 8 * lg;
#pragma unroll
        for (int s = 0; s < 8; ++s) {
            const float4 a0 = *(const float4*)(ap + 32 * s);
            const float4 a1 = *(const float4*)(ap + 32 * s + 4);
            const float4 c0 = *(const float4*)&basek[32 * s + 8 * lg];
            const float4 c4 = *(const float4*)&basek[32 * s + 8 * lg + 4];
            uint4 hv;
            hv.x = cvt2(fmaxf(a0.x + c0.x, 0.f), fmaxf(a0.y + c0.y, 0.f));
            hv.y = cvt2(fmaxf(a0.z + c0.z, 0.f), fmaxf(a0.w + c0.w, 0.f));
            hv.z = cvt2(fmaxf(a1.x + c4.x, 0.f), fmaxf(a1.y + c4.y, 0.f));
            hv.w = cvt2(fmaxf(a1.z + c4.z, 0.f), fmaxf(a1.w + c4.w, 0.f));
            *(uint4*)&h1f[((w * 8 + s) * 64 + l) * 8] = hv;
        }
        // W2 B-fragments for this wave's n-slice (per-tile lifetime, dies at B end)
        s16x8 bfr[32];
#pragma unroll
        for (int s = 0; s < 8; ++s)
#pragma unroll
            for (int n = 0; n < 4; ++n)
                bfr[s * 4 + n] = *(const s16x8*)(w2fg +
                    (size_t)(((s * 16 + 4 * w + n) * 64 + l)) * 8);
        BAR_LDS();   // bar1: h1f ready

        // ---- phase B: mt-outer; acc bias-seeded; 128 MFMA/wave
#pragma unroll
        for (int mt = 0; mt < 4; ++mt) {
            s16x8 a[8];
#pragma unroll
            for (int s = 0; s < 8; ++s)
                a[s] = *(const s16x8*)&h1f[((mt * 8 + s) * 64 + l) * 8];
#pragma unroll
            for (int n = 0; n < 4; ++n) {
                f32x4 acc = {bias[n], bias[n], bias[n], bias[n]};
#pragma unroll
                for (int s = 0; s < 8; ++s)
                    acc = __builtin_amdgcn_mfma_f32_16x16x32_bf16(a[s], bfr[s * 4 + n], acc, 0, 0, 0);
                const int col = 64 * w + 16 * n + l15;
                const int jrow = 16 * mt + 4 * lg;
#pragma unroll
                for (int r = 0; r < 4; ++r)
                    h2s[(jrow + r) * 264 + col] = (short)bf_bits(fmaxf(acc[r], 0.f));
            }
        }
        BAR_LDS();   // bar2: h2s ready

        // ---- phase C: score2 = H2 @ w3q; combine with fp32 S1
        float4 s1v = make_float4(0.f, 0.f, 0.f, 0.f);
        if (l15 < 8)
            s1v = *(const float4*)(S1 + (size_t)l15 * (N * N) + (size_t)i * N
                                   + j0 + 16 * w + 4 * lg);
        f32x4 acc2 = {};
#pragma unroll
        for (int s = 0; s < 8; ++s) {
            const s16x8 a2 = *(const s16x8*)&h2s[(16 * w + l15) * 264 + 32 * s + 8 * lg];
            const s16x8 wq = *(const s16x8*)&w3qf[(s * 64 + l) * 8];
            acc2 = __builtin_amdgcn_mfma_f32_16x16x32_bf16(a2, wq, acc2, 0, 0, 0);
        }
        if (l15 < 8) {
            float4 sc;
            sc.x = (acc2[0] + s1v.x) * SCALE_INV;
            sc.y = (acc2[1] + s1v.y) * SCALE_INV;
            sc.z = (acc2[2] + s1v.z) * SCALE_INV;
            sc.w = (acc2[3] + s1v.w) * SCALE_INV;
            *(float4*)&slds[l15 * 68 + 16 * w + 4 * lg] = sc;
        }
        BAR_LDS();   // bar3: slds scores ready

        // ---- p-gen: wave w owns heads {w, w+4}; 2 exps/thread
        {
            const int h0 = w, h1 = w + 4;
            const float s0 = slds[h0 * 68 + l];
            const float s1 = slds[h1 * 68 + l];
            float m0 = s0, m1 = s1;
#pragma unroll
            for (int o = 1; o < 64; o <<= 1) {
                m0 = fmaxf(m0, __shfl_xor(m0, o));
                m1 = fmaxf(m1, __shfl_xor(m1, o));
            }
            const float M0 = hm[h0], M1 = hm[h1];
            const float nm0 = fmaxf(M0, m0), nm1 = fmaxf(M1, m1);
            const float p0 = __expf(s0 - nm0), p1 = __expf(s1 - nm1);
            plds[h0 * 68 + l] = p0;
            plds[h1 * 68 + l] = p1;
            float t0 = p0, t1 = p1;
#pragma unroll
            for (int o = 1; o < 64; o <<= 1) {
                t0 += __shfl_xor(t0, o);
                t1 += __shfl_xor(t1, o);
            }
            if (l == 0) {
                const float r0 = __expf(M0 - nm0), r1 = __expf(M1 - nm1);
                hresc[h0] = r0; hresc[h1] = r1;
                hpsum[h0] = hpsum[h0] * r0 + t0;
                hpsum[h1] = hpsum[h1] * r1 + t1;
                hm[h0] = nm0; hm[h1] = nm1;
            }
        }
        BAR_LDS();   // bar4: plds + per-head state ready

        // ---- phase D: PV accumulate (p from LDS broadcast, V bf16 from L2)
        {
            pv *= hresc[h];
            const unsigned short* vp = vrow + j0;
            const float* pp = &plds[h * 68];
#pragma unroll
            for (int c = 0; c < 8; ++c) {
                const s16x8 vv = *(const s16x8*)(vp + c * 8);
                const float4 pa = *(const float4*)(pp + 8 * c);
                const float4 pb = *(const float4*)(pp + 8 * c + 4);
                pv += pa.x * bf2f((unsigned short)vv[0]) + pa.y * bf2f((unsigned short)vv[1])
                    + pa.z * bf2f((unsigned short)vv[2]) + pa.w * bf2f((unsigned short)vv[3])
                    + pb.x * bf2f((unsigned short)vv[4]) + pb.y * bf2f((unsigned short)vv[5])
                    + pb.z * bf2f((unsigned short)vv[6]) + pb.w * bf2f((unsigned short)vv[7]);
            }
        }
        // no end-of-tile barrier: plds/hresc rewrite (p-gen t+1) is 3 barriers
        // away; h1f rewrite (phase A t+1) conflicts only with B reads (pre-bar2)
    }

    // ---------------- epilogue: normalize + WoT projection
    oa[t] = pv / hpsum[h];
    BAR_LDS();
    float r = bo[t];
    const float* wop = WoT + (size_t)t * HID;
#pragma unroll 4
    for (int k = 0; k < HID; k += 4) {
        const float4 ov = *(const float4*)&oa[k];
        const float4 wv = *(const float4*)(wop + k);
        r += ov.x * wv.x + ov.y * wv.y + ov.z * wv.z + ov.w * wv.w;
    }
    out[(size_t)i * HID + t] = r;
}

// ---------------------------------------------------------------------------
extern "C" void kernel_launch(void* const* d_in, const int* in_sizes, int n_in,
                              void* d_out, int out_size, void* d_ws, size_t ws_size,
                              hipStream_t stream)
{
    const float* x   = (const float*)d_in[0];
    const float* pos = (const float*)d_in[1];
    const float* Wq  = (const float*)d_in[2];
    const float* bq  = (const float*)d_in[3];
    const float* Wk  = (const float*)d_in[4];
    const float* bk  = (const float*)d_in[5];
    const float* Wv  = (const float*)d_in[6];
    const float* bv  = (const float*)d_in[7];
    const float* Wo  = (const float*)d_in[8];
    const float* bo  = (const float*)d_in[9];
    const float* W1  = (const float*)d_in[10];
    const float* b1  = (const float*)d_in[11];
    const float* W2  = (const float*)d_in[12];
    const float* b2  = (const float*)d_in[13];
    const float* W3  = (const float*)d_in[14];
    const float* b3  = (const float*)d_in[15];  // softmax-invariant, folded out
    (void)b3;
    float* out = (float*)d_out;

    char* ws = (char*)d_ws;
    float* Q  = (float*)(ws + 0);                            // 768*256 f32
    float* A  = (float*)(ws + 786432);                       // 768*256 f32
    float* Kt = (float*)(ws + 1572864);                      // 256*768 f32
    unsigned short* Vtb = (unsigned short*)(ws + 2359296);   // 256*768 bf16
    float* S1 = (float*)(ws + 2752512);                      // 8*768*768 f32
    unsigned short* w2f  = (unsigned short*)(ws + 21626880); // 65536 bf16
    unsigned short* w3qg = (unsigned short*)(ws + 21757952); // 768*4096 bf16
    float* WoT = (float*)(ws + 28049408);                    // 256*256 f32

    prep_kernel<<<1024, 256, 0, stream>>>(x, pos, Wq, bq, Wk, bk, Wv, bv,
                                          W1, W2, W3, Wo,
                                          Q, Kt, Vtb, A, w2f, WoT, w3qg);
    s1_kernel<<<288, 256, 0, stream>>>(Q, Kt, S1);
    fused_main_kernel<<<N, 256, 0, stream>>>(A, S1, Vtb, w2f, w3qg,
                                             b1, b2, WoT, bo, out);
}

// Round 17
// 211.859 us; speedup vs baseline: 1.2476x; 1.0755x over previous
//
#include <hip/hip_runtime.h>
#include <hip/hip_bf16.h>

#define N 768
#define IN_DIM 128
#define HID 256
#define HD 32
#define TJ 64
#define NT (N / TJ)
#define NTH (NT / 2)
#define SCALE_INV 0.17677669529663687f  // 1/sqrt(32)

typedef short s16x8 __attribute__((ext_vector_type(8)));
typedef float f32x4 __attribute__((ext_vector_type(4)));

__device__ __forceinline__ float bf2f(unsigned short s) {
    return __uint_as_float(((unsigned)s) << 16);
}
__device__ __forceinline__ unsigned short bf_bits(float f) {
    __hip_bfloat16 h = __float2bfloat16(f);
    union { __hip_bfloat16 h; unsigned short u; } c; c.h = h; return c.u;
}
__device__ __forceinline__ unsigned cvt2(float a, float b) {
    __hip_bfloat162 h2 = __float22bfloat162_rn(make_float2(a, b));
    union { __hip_bfloat162 h; unsigned u; } c; c.h = h2; return c.u;
}

// LDS-only barrier: waits own-wave LDS ops, leaves global loads in flight.
#define BAR_LDS() do { asm volatile("s_waitcnt lgkmcnt(0)" ::: "memory"); \
                       __builtin_amdgcn_s_barrier(); } while (0)

// ---------------------------------------------------------------------------
// kernel 1 (grid 1024):
//  blocks 0..767   : per-i prep -> Q f32; Kt = K^T f32; Vt = V^T bf16;
//                    A = pos@W1 f32; w3q fragments for row i
//  blocks 768..1023: pack W2 into MFMA B-frag order + transpose Wo
// ---------------------------------------------------------------------------
__global__ __launch_bounds__(256) void prep_kernel(
    const float* __restrict__ x, const float* __restrict__ pos,
    const float* __restrict__ Wq, const float* __restrict__ bq,
    const float* __restrict__ Wk, const float* __restrict__ bk,
    const float* __restrict__ Wv, const float* __restrict__ bv,
    const float* __restrict__ W1, const float* __restrict__ W2,
    const float* __restrict__ W3, const float* __restrict__ Wo,
    float* __restrict__ Q, float* __restrict__ Kt,
    unsigned short* __restrict__ Vt, float* __restrict__ A,
    unsigned short* __restrict__ w2f, float* __restrict__ WoT,
    unsigned short* __restrict__ w3qg)
{
    const int bx = blockIdx.x, t = threadIdx.x;
    __shared__ float xs[IN_DIM];
    __shared__ float ps[3];
    __shared__ float qrow[HID];

    if (bx >= N) {
        // pack W2 B-frags: w2f[((s*16+nt)*64+l)*8+e] = W2[32s+8(l>>4)+e][16nt+(l&15)]
        const int p = (bx - N) * 256 + t;               // 0..65535
        const int e = p & 7, l = (p >> 3) & 63, nt = (p >> 9) & 15, s = p >> 13;
        const int krow = 32 * s + 8 * (l >> 4) + e;     // contraction index
        const int ncol = 16 * nt + (l & 15);            // output n index
        w2f[p] = bf_bits(W2[krow * HID + ncol]);
        WoT[p] = Wo[(p & 255) * HID + (p >> 8)];        // WoT[t][k] = Wo[k][t]
        return;
    }

    const int i = bx;
    if (t < IN_DIM) xs[t] = x[i * IN_DIM + t];
    if (t < 3) ps[t] = pos[i * 3 + t];
    __syncthreads();
    float q = bq[t], k = bk[t], v = bv[t];
#pragma unroll 8
    for (int kk = 0; kk < IN_DIM; ++kk) {
        const float xv = xs[kk];
        q += xv * Wq[kk * HID + t];
        k += xv * Wk[kk * HID + t];
        v += xv * Wv[kk * HID + t];
    }
    const float a = ps[0] * W1[t] + ps[1] * W1[HID + t] + ps[2] * W1[2 * HID + t];
    Q[i * HID + t] = q;
    Kt[(size_t)t * N + i] = k;
    Vt[(size_t)t * N + i] = bf_bits(v);
    A[i * HID + t] = a;
    qrow[t] = q;
    __syncthreads();

    // w3q frags: w3q[h][k] = sum_d W3[k][d]*q[h*32+d], B-frag order
    const int l = t & 63, sp = t >> 6, lg = l >> 4, hh = l & 15;
#pragma unroll
    for (int ss = 0; ss < 2; ++ss) {
        const int s = 2 * sp + ss;
        s16x8 frag = {0, 0, 0, 0, 0, 0, 0, 0};
        if (hh < 8) {
#pragma unroll
            for (int e = 0; e < 8; ++e) {
                const int kk = 32 * s + 8 * lg + e;
                const float* w3p = W3 + kk * HD;
                float acc = 0.f;
#pragma unroll
                for (int d0 = 0; d0 < 32; d0 += 4) {
                    const float4 wv = *(const float4*)(w3p + d0);
                    acc += wv.x * qrow[hh * HD + d0] + wv.y * qrow[hh * HD + d0 + 1]
                         + wv.z * qrow[hh * HD + d0 + 2] + wv.w * qrow[hh * HD + d0 + 3];
                }
                frag[e] = (short)bf_bits(acc);
            }
        }
        *(s16x8*)(w3qg + (size_t)i * 4096 + (size_t)(s * 64 + l) * 8) = frag;
    }
}

// ---------------------------------------------------------------------------
// kernel 2: S1[h][i][j] = q_i,h . k_j,h (f32). 32 i x 64 j x 8 h per block.
// ---------------------------------------------------------------------------
__global__ __launch_bounds__(256) void s1_kernel(
    const float* __restrict__ Q, const float* __restrict__ Kt,
    float* __restrict__ S1)
{
    const int t = threadIdx.x;
    const int i0 = (blockIdx.x / 12) * 32;
    const int j0 = (blockIdx.x % 12) * 64;
    __shared__ float qTs[256 * 36];   // [d'][i], row stride 36, XOR-swizzled chunks

    {
        const int iq = t & 31;
        const int dbase = (t >> 5) * 32;
        const int xk = t >> 5;
        const int colsw = (((iq >> 2) ^ xk) << 2) + (iq & 3);
        const float* qp = Q + (size_t)(i0 + iq) * HID + dbase;
#pragma unroll
        for (int cc = 0; cc < 8; ++cc) {
            const float4 qv = *(const float4*)(qp + 4 * cc);
            qTs[(dbase + 4 * cc + 0) * 36 + colsw] = qv.x;
            qTs[(dbase + 4 * cc + 1) * 36 + colsw] = qv.y;
            qTs[(dbase + 4 * cc + 2) * 36 + colsw] = qv.z;
            qTs[(dbase + 4 * cc + 3) * 36 + colsw] = qv.w;
        }
    }
    __syncthreads();

    const int h = t >> 5, jj = t & 31;
    const int j1 = j0 + jj, j2 = j0 + jj + 32;
    f32x4 acc0[8] = {}, acc1[8] = {};
    const float* kp = Kt + (size_t)(32 * h) * N + j1;
#pragma unroll 4
    for (int d = 0; d < 32; ++d) {
        const float k0 = kp[(size_t)d * N];
        const float k1 = kp[(size_t)d * N + 32];
        const float* qrow = &qTs[(32 * h + d) * 36];
#pragma unroll
        for (int ic = 0; ic < 8; ++ic) {
            const f32x4 qv = *(const f32x4*)&qrow[(ic ^ h) << 2];
            acc0[ic] += qv * k0;
            acc1[ic] += qv * k1;
        }
    }
    float* op = S1 + (size_t)h * (N * N) + (size_t)i0 * N;
#pragma unroll
    for (int ic = 0; ic < 8; ++ic)
#pragma unroll
        for (int u = 0; u < 4; ++u) {
            op[(size_t)(4 * ic + u) * N + j1] = acc0[ic][u];
            op[(size_t)(4 * ic + u) * N + j2] = acc1[ic][u];
        }
}

// ---------------------------------------------------------------------------
// kernel 3: fused main, SPLIT-J — block b handles (i = b>>1, j-half = b&1),
// 6 tiles each. Grid 1536 at 2 blocks/CU = 3 exact residency fills (no tail).
// Per-block structure identical to r13 (4 waves, 4 LDS-only barriers/tile,
// mt-outer B, bfr[32] dies at B end). Epilogue writes partial softmax state.
// ---------------------------------------------------------------------------
__global__ __launch_bounds__(256, 2) void fused_main_kernel(
    const float* __restrict__ Ag, const float* __restrict__ S1,
    const unsigned short* __restrict__ Vt,
    const unsigned short* __restrict__ w2fg, const unsigned short* __restrict__ w3qg,
    const float* __restrict__ b1, const float* __restrict__ b2,
    float* __restrict__ pv0g, float* __restrict__ pv1g,
    float* __restrict__ psump, float* __restrict__ mp)
{
    const int bid = blockIdx.x;
    const int i = bid >> 1, jh = bid & 1;
    const int t = threadIdx.x;
    const int w = t >> 6, l = t & 63;
    const int lg = l >> 4, l15 = l & 15;

    __shared__ __align__(16) short h1f[4 * 8 * 64 * 8];   // 32 KB  H1 A-frags
    __shared__ __align__(16) short h2s[64 * 264];          // 33 KB  H2 [j][k]
    __shared__ __align__(16) short w3qf[8 * 64 * 8];       // 8 KB   w3q B-frags
    __shared__ __align__(16) float slds[8 * 68];           // scores [h][jj]
    __shared__ __align__(16) float plds[8 * 68];           // probs  [h][jj]
    __shared__ float basek[HID];
    __shared__ float hm[8], hpsum[8], hresc[8];

    // ---------------- prolog
    basek[t] = b1[t] - Ag[(size_t)i * HID + t];
    {
        const int c0 = t, c1 = t + 256;
        *(s16x8*)&w3qf[c0 * 8] = *(const s16x8*)(w3qg + (size_t)i * 4096 + (size_t)c0 * 8);
        *(s16x8*)&w3qf[c1 * 8] = *(const s16x8*)(w3qg + (size_t)i * 4096 + (size_t)c1 * 8);
    }
    if (t < 8) { hm[t] = -3.0e38f; hpsum[t] = 0.f; }
    float bias[4];
#pragma unroll
    for (int n = 0; n < 4; ++n) bias[n] = b2[64 * w + 16 * n + l15];

    float pv = 0.f;
    const int h = t >> 5;
    const unsigned short* vrow = Vt + (size_t)t * N;
    BAR_LDS();

#pragma unroll 1
    for (int tt = 0; tt < NTH; ++tt) {
        const int j0 = (jh * NTH + tt) * TJ;

        // ---- phase A: H1 = relu(A[j] - A[i] + b1) in A-fragment order
        const int jj = 16 * w + l15;
        const float* ap = Ag + (size_t)(j0 + jj) * HID + 8 * lg;
#pragma unroll
        for (int s = 0; s < 8; ++s) {
            const float4 a0 = *(const float4*)(ap + 32 * s);
            const float4 a1 = *(const float4*)(ap + 32 * s + 4);
            const float4 c0 = *(const float4*)&basek[32 * s + 8 * lg];
            const float4 c4 = *(const float4*)&basek[32 * s + 8 * lg + 4];
            uint4 hv;
            hv.x = cvt2(fmaxf(a0.x + c0.x, 0.f), fmaxf(a0.y + c0.y, 0.f));
            hv.y = cvt2(fmaxf(a0.z + c0.z, 0.f), fmaxf(a0.w + c0.w, 0.f));
            hv.z = cvt2(fmaxf(a1.x + c4.x, 0.f), fmaxf(a1.y + c4.y, 0.f));
            hv.w = cvt2(fmaxf(a1.z + c4.z, 0.f), fmaxf(a1.w + c4.w, 0.f));
            *(uint4*)&h1f[((w * 8 + s) * 64 + l) * 8] = hv;
        }
        // W2 B-fragments for this wave's n-slice (per-tile lifetime, dies at B end)
        s16x8 bfr[32];
#pragma unroll
        for (int s = 0; s < 8; ++s)
#pragma unroll
            for (int n = 0; n < 4; ++n)
                bfr[s * 4 + n] = *(const s16x8*)(w2fg +
                    (size_t)(((s * 16 + 4 * w + n) * 64 + l)) * 8);
        BAR_LDS();   // bar1: h1f ready

        // ---- phase B: mt-outer; acc bias-seeded; 128 MFMA/wave
#pragma unroll
        for (int mt = 0; mt < 4; ++mt) {
            s16x8 a[8];
#pragma unroll
            for (int s = 0; s < 8; ++s)
                a[s] = *(const s16x8*)&h1f[((mt * 8 + s) * 64 + l) * 8];
#pragma unroll
            for (int n = 0; n < 4; ++n) {
                f32x4 acc = {bias[n], bias[n], bias[n], bias[n]};
#pragma unroll
                for (int s = 0; s < 8; ++s)
                    acc = __builtin_amdgcn_mfma_f32_16x16x32_bf16(a[s], bfr[s * 4 + n], acc, 0, 0, 0);
                const int col = 64 * w + 16 * n + l15;
                const int jrow = 16 * mt + 4 * lg;
#pragma unroll
                for (int r = 0; r < 4; ++r)
                    h2s[(jrow + r) * 264 + col] = (short)bf_bits(fmaxf(acc[r], 0.f));
            }
        }
        BAR_LDS();   // bar2: h2s ready

        // ---- phase C: score2 = H2 @ w3q; combine with fp32 S1
        float4 s1v = make_float4(0.f, 0.f, 0.f, 0.f);
        if (l15 < 8)
            s1v = *(const float4*)(S1 + (size_t)l15 * (N * N) + (size_t)i * N
                                   + j0 + 16 * w + 4 * lg);
        f32x4 acc2 = {};
#pragma unroll
        for (int s = 0; s < 8; ++s) {
            const s16x8 a2 = *(const s16x8*)&h2s[(16 * w + l15) * 264 + 32 * s + 8 * lg];
            const s16x8 wq = *(const s16x8*)&w3qf[(s * 64 + l) * 8];
            acc2 = __builtin_amdgcn_mfma_f32_16x16x32_bf16(a2, wq, acc2, 0, 0, 0);
        }
        if (l15 < 8) {
            float4 sc;
            sc.x = (acc2[0] + s1v.x) * SCALE_INV;
            sc.y = (acc2[1] + s1v.y) * SCALE_INV;
            sc.z = (acc2[2] + s1v.z) * SCALE_INV;
            sc.w = (acc2[3] + s1v.w) * SCALE_INV;
            *(float4*)&slds[l15 * 68 + 16 * w + 4 * lg] = sc;
        }
        BAR_LDS();   // bar3: slds scores ready

        // ---- p-gen: wave w owns heads {w, w+4}; 2 exps/thread
        {
            const int h0 = w, h1 = w + 4;
            const float s0 = slds[h0 * 68 + l];
            const float s1 = slds[h1 * 68 + l];
            float m0 = s0, m1 = s1;
#pragma unroll
            for (int o = 1; o < 64; o <<= 1) {
                m0 = fmaxf(m0, __shfl_xor(m0, o));
                m1 = fmaxf(m1, __shfl_xor(m1, o));
            }
            const float M0 = hm[h0], M1 = hm[h1];
            const float nm0 = fmaxf(M0, m0), nm1 = fmaxf(M1, m1);
            const float p0 = __expf(s0 - nm0), p1 = __expf(s1 - nm1);
            plds[h0 * 68 + l] = p0;
            plds[h1 * 68 + l] = p1;
            float t0 = p0, t1 = p1;
#pragma unroll
            for (int o = 1; o < 64; o <<= 1) {
                t0 += __shfl_xor(t0, o);
                t1 += __shfl_xor(t1, o);
            }
            if (l == 0) {
                const float r0 = __expf(M0 - nm0), r1 = __expf(M1 - nm1);
                hresc[h0] = r0; hresc[h1] = r1;
                hpsum[h0] = hpsum[h0] * r0 + t0;
                hpsum[h1] = hpsum[h1] * r1 + t1;
                hm[h0] = nm0; hm[h1] = nm1;
            }
        }
        BAR_LDS();   // bar4: plds + per-head state ready

        // ---- phase D: PV accumulate (p from LDS broadcast, V bf16 from L2)
        {
            pv *= hresc[h];
            const unsigned short* vp = vrow + j0;
            const float* pp = &plds[h * 68];
#pragma unroll
            for (int c = 0; c < 8; ++c) {
                const s16x8 vv = *(const s16x8*)(vp + c * 8);
                const float4 pa = *(const float4*)(pp + 8 * c);
                const float4 pb = *(const float4*)(pp + 8 * c + 4);
                pv += pa.x * bf2f((unsigned short)vv[0]) + pa.y * bf2f((unsigned short)vv[1])
                    + pa.z * bf2f((unsigned short)vv[2]) + pa.w * bf2f((unsigned short)vv[3])
                    + pb.x * bf2f((unsigned short)vv[4]) + pb.y * bf2f((unsigned short)vv[5])
                    + pb.z * bf2f((unsigned short)vv[6]) + pb.w * bf2f((unsigned short)vv[7]);
            }
        }
        // no end-of-tile barrier: plds/hresc rewrite (p-gen t+1) is 3 barriers
        // away; h1f rewrite (phase A t+1) conflicts only with B reads (pre-bar2)
    }

    // ---------------- epilogue: write partial (pv, psum, m) for this half
    float* pvb = jh ? pv1g : pv0g;
    pvb[(size_t)i * HID + t] = pv;
    if (t < 8) {
        psump[(size_t)bid * 8 + t] = hpsum[t];
        mp[(size_t)bid * 8 + t] = hm[t];
    }
}

// ---------------------------------------------------------------------------
// kernel 4: combine halves (flash-style state merge) + Wo projection.
// ---------------------------------------------------------------------------
__global__ __launch_bounds__(256) void combine_kernel(
    const float* __restrict__ pv0g, const float* __restrict__ pv1g,
    const float* __restrict__ psump, const float* __restrict__ mp,
    const float* __restrict__ WoT, const float* __restrict__ bo,
    float* __restrict__ out)
{
    const int i = blockIdx.x, t = threadIdx.x;
    const int h = t >> 5;
    __shared__ float oa[HID];

    const float m0 = mp[(size_t)(2 * i) * 8 + h];
    const float m1 = mp[(size_t)(2 * i + 1) * 8 + h];
    const float ms = fmaxf(m0, m1);
    const float e0 = __expf(m0 - ms), e1 = __expf(m1 - ms);
    const float num = pv0g[(size_t)i * HID + t] * e0 + pv1g[(size_t)i * HID + t] * e1;
    const float den = psump[(size_t)(2 * i) * 8 + h] * e0
                    + psump[(size_t)(2 * i + 1) * 8 + h] * e1;
    oa[t] = num / den;
    __syncthreads();

    float r = bo[t];
    const float* wop = WoT + (size_t)t * HID;
#pragma unroll 4
    for (int k = 0; k < HID; k += 4) {
        const float4 ov = *(const float4*)&oa[k];
        const float4 wv = *(const float4*)(wop + k);
        r += ov.x * wv.x + ov.y * wv.y + ov.z * wv.z + ov.w * wv.w;
    }
    out[(size_t)i * HID + t] = r;
}

// ---------------------------------------------------------------------------
extern "C" void kernel_launch(void* const* d_in, const int* in_sizes, int n_in,
                              void* d_out, int out_size, void* d_ws, size_t ws_size,
                              hipStream_t stream)
{
    const float* x   = (const float*)d_in[0];
    const float* pos = (const float*)d_in[1];
    const float* Wq  = (const float*)d_in[2];
    const float* bq  = (const float*)d_in[3];
    const float* Wk  = (const float*)d_in[4];
    const float* bk  = (const float*)d_in[5];
    const float* Wv  = (const float*)d_in[6];
    const float* bv  = (const float*)d_in[7];
    const float* Wo  = (const float*)d_in[8];
    const float* bo  = (const float*)d_in[9];
    const float* W1  = (const float*)d_in[10];
    const float* b1  = (const float*)d_in[11];
    const float* W2  = (const float*)d_in[12];
    const float* b2  = (const float*)d_in[13];
    const float* W3  = (const float*)d_in[14];
    const float* b3  = (const float*)d_in[15];  // softmax-invariant, folded out
    (void)b3;
    float* out = (float*)d_out;

    char* ws = (char*)d_ws;
    float* Q  = (float*)(ws + 0);                            // 768*256 f32
    float* A  = (float*)(ws + 786432);                       // 768*256 f32
    float* Kt = (float*)(ws + 1572864);                      // 256*768 f32
    unsigned short* Vtb = (unsigned short*)(ws + 2359296);   // 256*768 bf16
    float* S1 = (float*)(ws + 2752512);                      // 8*768*768 f32
    unsigned short* w2f  = (unsigned short*)(ws + 21626880); // 65536 bf16
    unsigned short* w3qg = (unsigned short*)(ws + 21757952); // 768*4096 bf16
    float* WoT = (float*)(ws + 28049408);                    // 256*256 f32
    // partial buffers: pv halves overlay Q/Kt (dead after s1_kernel)
    float* pv0g  = (float*)(ws + 0);                         // 768*256 f32 (over Q)
    float* pv1g  = (float*)(ws + 1572864);                   // 768*256 f32 (over Kt)
    float* psump = (float*)(ws + 28311552);                  // 1536*8 f32
    float* mp    = (float*)(ws + 28360704);                  // 1536*8 f32

    prep_kernel<<<1024, 256, 0, stream>>>(x, pos, Wq, bq, Wk, bk, Wv, bv,
                                          W1, W2, W3, Wo,
                                          Q, Kt, Vtb, A, w2f, WoT, w3qg);
    s1_kernel<<<288, 256, 0, stream>>>(Q, Kt, S1);
    fused_main_kernel<<<2 * N, 256, 0, stream>>>(A, S1, Vtb, w2f, w3qg,
                                                 b1, b2, pv0g, pv1g, psump, mp);
    combine_kernel<<<N, 256, 0, stream>>>(pv0g, pv1g, psump, mp, WoT, bo, out);
}

// Round 18
// 209.189 us; speedup vs baseline: 1.2635x; 1.0128x over previous
//
#include <hip/hip_runtime.h>
#include <hip/hip_bf16.h>

#define N 768
#define IN_DIM 128
#define HID 256
#define HD 32
#define TJ 64
#define NT (N / TJ)
#define NTH (NT / 2)
#define SCALE_INV 0.17677669529663687f  // 1/sqrt(32)

typedef short s16x8 __attribute__((ext_vector_type(8)));
typedef float f32x4 __attribute__((ext_vector_type(4)));

__device__ __forceinline__ float bf2f(unsigned short s) {
    return __uint_as_float(((unsigned)s) << 16);
}
__device__ __forceinline__ unsigned short bf_bits(float f) {
    __hip_bfloat16 h = __float2bfloat16(f);
    union { __hip_bfloat16 h; unsigned short u; } c; c.h = h; return c.u;
}
__device__ __forceinline__ unsigned cvt2(float a, float b) {
    __hip_bfloat162 h2 = __float22bfloat162_rn(make_float2(a, b));
    union { __hip_bfloat162 h; unsigned u; } c; c.h = h2; return c.u;
}

// LDS-only barrier: waits own-wave LDS ops, leaves global loads in flight.
#define BAR_LDS() do { asm volatile("s_waitcnt lgkmcnt(0)" ::: "memory"); \
                       __builtin_amdgcn_s_barrier(); } while (0)

// ---------------------------------------------------------------------------
// kernel 1 (grid 1024):
//  blocks 0..767   : per-i prep -> Q f32; Kt = K^T f32; Vt = V^T bf16;
//                    A = pos@W1 f32; w3q fragments for row i
//  blocks 768..1023: pack W2 into MFMA B-frag order + transpose Wo
// ---------------------------------------------------------------------------
__global__ __launch_bounds__(256) void prep_kernel(
    const float* __restrict__ x, const float* __restrict__ pos,
    const float* __restrict__ Wq, const float* __restrict__ bq,
    const float* __restrict__ Wk, const float* __restrict__ bk,
    const float* __restrict__ Wv, const float* __restrict__ bv,
    const float* __restrict__ W1, const float* __restrict__ W2,
    const float* __restrict__ W3, const float* __restrict__ Wo,
    float* __restrict__ Q, float* __restrict__ Kt,
    unsigned short* __restrict__ Vt, float* __restrict__ A,
    unsigned short* __restrict__ w2f, float* __restrict__ WoT,
    unsigned short* __restrict__ w3qg)
{
    const int bx = blockIdx.x, t = threadIdx.x;
    __shared__ float xs[IN_DIM];
    __shared__ float ps[3];
    __shared__ float qrow[HID];

    if (bx >= N) {
        // pack W2 B-frags: w2f[((s*16+nt)*64+l)*8+e] = W2[32s+8(l>>4)+e][16nt+(l&15)]
        const int p = (bx - N) * 256 + t;               // 0..65535
        const int e = p & 7, l = (p >> 3) & 63, nt = (p >> 9) & 15, s = p >> 13;
        const int krow = 32 * s + 8 * (l >> 4) + e;     // contraction index
        const int ncol = 16 * nt + (l & 15);            // output n index
        w2f[p] = bf_bits(W2[krow * HID + ncol]);
        WoT[p] = Wo[(p & 255) * HID + (p >> 8)];        // WoT[t][k] = Wo[k][t]
        return;
    }

    const int i = bx;
    if (t < IN_DIM) xs[t] = x[i * IN_DIM + t];
    if (t < 3) ps[t] = pos[i * 3 + t];
    __syncthreads();
    float q = bq[t], k = bk[t], v = bv[t];
#pragma unroll 8
    for (int kk = 0; kk < IN_DIM; ++kk) {
        const float xv = xs[kk];
        q += xv * Wq[kk * HID + t];
        k += xv * Wk[kk * HID + t];
        v += xv * Wv[kk * HID + t];
    }
    const float a = ps[0] * W1[t] + ps[1] * W1[HID + t] + ps[2] * W1[2 * HID + t];
    Q[i * HID + t] = q;
    Kt[(size_t)t * N + i] = k;
    Vt[(size_t)t * N + i] = bf_bits(v);
    A[i * HID + t] = a;
    qrow[t] = q;
    __syncthreads();

    // w3q frags: w3q[h][k] = sum_d W3[k][d]*q[h*32+d], B-frag order
    const int l = t & 63, sp = t >> 6, lg = l >> 4, hh = l & 15;
#pragma unroll
    for (int ss = 0; ss < 2; ++ss) {
        const int s = 2 * sp + ss;
        s16x8 frag = {0, 0, 0, 0, 0, 0, 0, 0};
        if (hh < 8) {
#pragma unroll
            for (int e = 0; e < 8; ++e) {
                const int kk = 32 * s + 8 * lg + e;
                const float* w3p = W3 + kk * HD;
                float acc = 0.f;
#pragma unroll
                for (int d0 = 0; d0 < 32; d0 += 4) {
                    const float4 wv = *(const float4*)(w3p + d0);
                    acc += wv.x * qrow[hh * HD + d0] + wv.y * qrow[hh * HD + d0 + 1]
                         + wv.z * qrow[hh * HD + d0 + 2] + wv.w * qrow[hh * HD + d0 + 3];
                }
                frag[e] = (short)bf_bits(acc);
            }
        }
        *(s16x8*)(w3qg + (size_t)i * 4096 + (size_t)(s * 64 + l) * 8) = frag;
    }
}

// ---------------------------------------------------------------------------
// kernel 2: S1[h][i][j] = q_i,h . k_j,h (f32). 32 i x 64 j x 8 h per block.
// ---------------------------------------------------------------------------
__global__ __launch_bounds__(256) void s1_kernel(
    const float* __restrict__ Q, const float* __restrict__ Kt,
    float* __restrict__ S1)
{
    const int t = threadIdx.x;
    const int i0 = (blockIdx.x / 12) * 32;
    const int j0 = (blockIdx.x % 12) * 64;
    __shared__ float qTs[256 * 36];   // [d'][i], row stride 36, XOR-swizzled chunks

    {
        const int iq = t & 31;
        const int dbase = (t >> 5) * 32;
        const int xk = t >> 5;
        const int colsw = (((iq >> 2) ^ xk) << 2) + (iq & 3);
        const float* qp = Q + (size_t)(i0 + iq) * HID + dbase;
#pragma unroll
        for (int cc = 0; cc < 8; ++cc) {
            const float4 qv = *(const float4*)(qp + 4 * cc);
            qTs[(dbase + 4 * cc + 0) * 36 + colsw] = qv.x;
            qTs[(dbase + 4 * cc + 1) * 36 + colsw] = qv.y;
            qTs[(dbase + 4 * cc + 2) * 36 + colsw] = qv.z;
            qTs[(dbase + 4 * cc + 3) * 36 + colsw] = qv.w;
        }
    }
    __syncthreads();

    const int h = t >> 5, jj = t & 31;
    const int j1 = j0 + jj, j2 = j0 + jj + 32;
    f32x4 acc0[8] = {}, acc1[8] = {};
    const float* kp = Kt + (size_t)(32 * h) * N + j1;
#pragma unroll 4
    for (int d = 0; d < 32; ++d) {
        const float k0 = kp[(size_t)d * N];
        const float k1 = kp[(size_t)d * N + 32];
        const float* qrow = &qTs[(32 * h + d) * 36];
#pragma unroll
        for (int ic = 0; ic < 8; ++ic) {
            const f32x4 qv = *(const f32x4*)&qrow[(ic ^ h) << 2];
            acc0[ic] += qv * k0;
            acc1[ic] += qv * k1;
        }
    }
    float* op = S1 + (size_t)h * (N * N) + (size_t)i0 * N;
#pragma unroll
    for (int ic = 0; ic < 8; ++ic)
#pragma unroll
        for (int u = 0; u < 4; ++u) {
            op[(size_t)(4 * ic + u) * N + j1] = acc0[ic][u];
            op[(size_t)(4 * ic + u) * N + j2] = acc1[ic][u];
        }
}

// ---------------------------------------------------------------------------
// kernel 3: fused main, SPLIT-J — block b handles (i = b>>1, j-half = b&1),
// 6 tiles each, grid 1536 = 3 exact residency fills. 3 LDS-only barriers/tile
// (bar4 removed: PV head remapped to hsel = w + 4*(l>=32) so p-gen -> PV is
// wave-local). V prefetched after bar3 (zero-barrier liveness, latency hides
// under p-gen). S1 load hoisted to phase A. bfr[32] dies at B end.
// ---------------------------------------------------------------------------
__global__ __launch_bounds__(256, 2) void fused_main_kernel(
    const float* __restrict__ Ag, const float* __restrict__ S1,
    const unsigned short* __restrict__ Vt,
    const unsigned short* __restrict__ w2fg, const unsigned short* __restrict__ w3qg,
    const float* __restrict__ b1, const float* __restrict__ b2,
    float* __restrict__ pv0g, float* __restrict__ pv1g,
    float* __restrict__ psump, float* __restrict__ mp)
{
    const int bid = blockIdx.x;
    const int i = bid >> 1, jhalf = bid & 1;
    const int t = threadIdx.x;
    const int w = t >> 6, l = t & 63;
    const int lg = l >> 4, l15 = l & 15;

    __shared__ __align__(16) short h1f[4 * 8 * 64 * 8];   // 32 KB  H1 A-frags
    __shared__ __align__(16) short h2s[64 * 264];          // 33 KB  H2 [j][k]
    __shared__ __align__(16) short w3qf[8 * 64 * 8];       // 8 KB   w3q B-frags
    __shared__ __align__(16) float slds[8 * 68];           // scores [h][jj]
    __shared__ __align__(16) float plds[8 * 68];           // probs  [h][jj]
    __shared__ float basek[HID];
    __shared__ float hm[8], hpsum[8], hresc[8];

    // ---------------- prolog
    basek[t] = b1[t] - Ag[(size_t)i * HID + t];
    {
        const int c0 = t, c1 = t + 256;
        *(s16x8*)&w3qf[c0 * 8] = *(const s16x8*)(w3qg + (size_t)i * 4096 + (size_t)c0 * 8);
        *(s16x8*)&w3qf[c1 * 8] = *(const s16x8*)(w3qg + (size_t)i * 4096 + (size_t)c1 * 8);
    }
    if (t < 8) { hm[t] = -3.0e38f; hpsum[t] = 0.f; }
    float bias[4];
#pragma unroll
    for (int n = 0; n < 4; ++n) bias[n] = b2[64 * w + 16 * n + l15];

    float pv = 0.f;
    // PV head remap: wave w serves its OWN p-gen heads {w, w+4}.
    const int hsel = w + ((l >> 5) << 2);       // head this thread accumulates
    const int hid2 = hsel * 32 + (l & 31);      // output hidden index
    const unsigned short* vrow = Vt + (size_t)hid2 * N;
    BAR_LDS();

#pragma unroll 1
    for (int tt = 0; tt < NTH; ++tt) {
        const int j0 = (jhalf * NTH + tt) * TJ;

        // ---- phase A: H1 = relu(A[j] - A[i] + b1) in A-fragment order
        const int jj = 16 * w + l15;
        const float* ap = Ag + (size_t)(j0 + jj) * HID + 8 * lg;
#pragma unroll
        for (int s = 0; s < 8; ++s) {
            const float4 a0 = *(const float4*)(ap + 32 * s);
            const float4 a1 = *(const float4*)(ap + 32 * s + 4);
            const float4 c0 = *(const float4*)&basek[32 * s + 8 * lg];
            const float4 c4 = *(const float4*)&basek[32 * s + 8 * lg + 4];
            uint4 hv;
            hv.x = cvt2(fmaxf(a0.x + c0.x, 0.f), fmaxf(a0.y + c0.y, 0.f));
            hv.y = cvt2(fmaxf(a0.z + c0.z, 0.f), fmaxf(a0.w + c0.w, 0.f));
            hv.z = cvt2(fmaxf(a1.x + c4.x, 0.f), fmaxf(a1.y + c4.y, 0.f));
            hv.w = cvt2(fmaxf(a1.z + c4.z, 0.f), fmaxf(a1.w + c4.w, 0.f));
            *(uint4*)&h1f[((w * 8 + s) * 64 + l) * 8] = hv;
        }
        // S1 tile issued here (consumed in phase C; 4 regs across 2 barriers)
        float4 s1v = make_float4(0.f, 0.f, 0.f, 0.f);
        if (l15 < 8)
            s1v = *(const float4*)(S1 + (size_t)l15 * (N * N) + (size_t)i * N
                                   + j0 + 16 * w + 4 * lg);
        // W2 B-fragments for this wave's n-slice (per-tile lifetime, dies at B end)
        s16x8 bfr[32];
#pragma unroll
        for (int s = 0; s < 8; ++s)
#pragma unroll
            for (int n = 0; n < 4; ++n)
                bfr[s * 4 + n] = *(const s16x8*)(w2fg +
                    (size_t)(((s * 16 + 4 * w + n) * 64 + l)) * 8);
        BAR_LDS();   // bar1: h1f ready

        // ---- phase B: mt-outer; acc bias-seeded; 128 MFMA/wave
#pragma unroll
        for (int mt = 0; mt < 4; ++mt) {
            s16x8 a[8];
#pragma unroll
            for (int s = 0; s < 8; ++s)
                a[s] = *(const s16x8*)&h1f[((mt * 8 + s) * 64 + l) * 8];
#pragma unroll
            for (int n = 0; n < 4; ++n) {
                f32x4 acc = {bias[n], bias[n], bias[n], bias[n]};
#pragma unroll
                for (int s = 0; s < 8; ++s)
                    acc = __builtin_amdgcn_mfma_f32_16x16x32_bf16(a[s], bfr[s * 4 + n], acc, 0, 0, 0);
                const int col = 64 * w + 16 * n + l15;
                const int jrow = 16 * mt + 4 * lg;
#pragma unroll
                for (int r = 0; r < 4; ++r)
                    h2s[(jrow + r) * 264 + col] = (short)bf_bits(fmaxf(acc[r], 0.f));
            }
        }
        BAR_LDS();   // bar2: h2s ready

        // ---- phase C: score2 = H2 @ w3q; combine with fp32 S1
        f32x4 acc2 = {};
#pragma unroll
        for (int s = 0; s < 8; ++s) {
            const s16x8 a2 = *(const s16x8*)&h2s[(16 * w + l15) * 264 + 32 * s + 8 * lg];
            const s16x8 wq = *(const s16x8*)&w3qf[(s * 64 + l) * 8];
            acc2 = __builtin_amdgcn_mfma_f32_16x16x32_bf16(a2, wq, acc2, 0, 0, 0);
        }
        if (l15 < 8) {
            float4 sc;
            sc.x = (acc2[0] + s1v.x) * SCALE_INV;
            sc.y = (acc2[1] + s1v.y) * SCALE_INV;
            sc.z = (acc2[2] + s1v.z) * SCALE_INV;
            sc.w = (acc2[3] + s1v.w) * SCALE_INV;
            *(float4*)&slds[l15 * 68 + 16 * w + 4 * lg] = sc;
        }
        BAR_LDS();   // bar3: slds scores ready

        // ---- V prefetch (zero-barrier liveness; latency hides under p-gen)
        s16x8 vv[8];
        {
            const unsigned short* vp = vrow + j0;
#pragma unroll
            for (int c = 0; c < 8; ++c) vv[c] = *(const s16x8*)(vp + c * 8);
        }

        // ---- p-gen: wave w owns heads {w, w+4}; 2 exps/thread
        {
            const int h0 = w, h1 = w + 4;
            const float s0 = slds[h0 * 68 + l];
            const float s1 = slds[h1 * 68 + l];
            float m0 = s0, m1 = s1;
#pragma unroll
            for (int o = 1; o < 64; o <<= 1) {
                m0 = fmaxf(m0, __shfl_xor(m0, o));
                m1 = fmaxf(m1, __shfl_xor(m1, o));
            }
            const float M0 = hm[h0], M1 = hm[h1];
            const float nm0 = fmaxf(M0, m0), nm1 = fmaxf(M1, m1);
            const float p0 = __expf(s0 - nm0), p1 = __expf(s1 - nm1);
            plds[h0 * 68 + l] = p0;
            plds[h1 * 68 + l] = p1;
            float t0 = p0, t1 = p1;
#pragma unroll
            for (int o = 1; o < 64; o <<= 1) {
                t0 += __shfl_xor(t0, o);
                t1 += __shfl_xor(t1, o);
            }
            if (l == 0) {
                const float r0 = __expf(M0 - nm0), r1 = __expf(M1 - nm1);
                hresc[h0] = r0; hresc[h1] = r1;
                hpsum[h0] = hpsum[h0] * r0 + t0;
                hpsum[h1] = hpsum[h1] * r1 + t1;
                hm[h0] = nm0; hm[h1] = nm1;
            }
        }
        // own-wave fence: plds rows {w, w+4} + hresc written by this wave only
        asm volatile("s_waitcnt lgkmcnt(0)" ::: "memory");

        // ---- phase D: PV accumulate, wave-local (head hsel = w or w+4)
        {
            pv *= hresc[hsel];
            const float* pp = &plds[hsel * 68];
#pragma unroll
            for (int c = 0; c < 8; ++c) {
                const s16x8 vvv = vv[c];
                const float4 pa = *(const float4*)(pp + 8 * c);
                const float4 pb = *(const float4*)(pp + 8 * c + 4);
                pv += pa.x * bf2f((unsigned short)vvv[0]) + pa.y * bf2f((unsigned short)vvv[1])
                    + pa.z * bf2f((unsigned short)vvv[2]) + pa.w * bf2f((unsigned short)vvv[3])
                    + pb.x * bf2f((unsigned short)vvv[4]) + pb.y * bf2f((unsigned short)vvv[5])
                    + pb.z * bf2f((unsigned short)vvv[6]) + pb.w * bf2f((unsigned short)vvv[7]);
            }
        }
        // no bar4: plds/hresc rewrite (p-gen t+1) is wave-local and behind
        // bar3(t+1); slds rewrite (phase C t+1) is behind bar2(t+1) which
        // requires all waves past p-gen(t) (they must pass bar1(t+1) first)
    }

    // ---------------- epilogue: write partial (pv, psum, m) for this half
    float* pvb = jhalf ? pv1g : pv0g;
    pvb[(size_t)i * HID + hid2] = pv;
    BAR_LDS();   // hm/hpsum from all waves' lane-0s visible
    if (t < 8) {
        psump[(size_t)bid * 8 + t] = hpsum[t];
        mp[(size_t)bid * 8 + t] = hm[t];
    }
}

// ---------------------------------------------------------------------------
// kernel 4: combine halves (flash-style state merge) + Wo projection.
// ---------------------------------------------------------------------------
__global__ __launch_bounds__(256) void combine_kernel(
    const float* __restrict__ pv0g, const float* __restrict__ pv1g,
    const float* __restrict__ psump, const float* __restrict__ mp,
    const float* __restrict__ WoT, const float* __restrict__ bo,
    float* __restrict__ out)
{
    const int i = blockIdx.x, t = threadIdx.x;
    const int h = t >> 5;
    __shared__ float oa[HID];

    const float m0 = mp[(size_t)(2 * i) * 8 + h];
    const float m1 = mp[(size_t)(2 * i + 1) * 8 + h];
    const float ms = fmaxf(m0, m1);
    const float e0 = __expf(m0 - ms), e1 = __expf(m1 - ms);
    const float num = pv0g[(size_t)i * HID + t] * e0 + pv1g[(size_t)i * HID + t] * e1;
    const float den = psump[(size_t)(2 * i) * 8 + h] * e0
                    + psump[(size_t)(2 * i + 1) * 8 + h] * e1;
    oa[t] = num / den;
    __syncthreads();

    float r = bo[t];
    const float* wop = WoT + (size_t)t * HID;
#pragma unroll 4
    for (int k = 0; k < HID; k += 4) {
        const float4 ov = *(const float4*)&oa[k];
        const float4 wv = *(const float4*)(wop + k);
        r += ov.x * wv.x + ov.y * wv.y + ov.z * wv.z + ov.w * wv.w;
    }
    out[(size_t)i * HID + t] = r;
}

// ---------------------------------------------------------------------------
extern "C" void kernel_launch(void* const* d_in, const int* in_sizes, int n_in,
                              void* d_out, int out_size, void* d_ws, size_t ws_size,
                              hipStream_t stream)
{
    const float* x   = (const float*)d_in[0];
    const float* pos = (const float*)d_in[1];
    const float* Wq  = (const float*)d_in[2];
    const float* bq  = (const float*)d_in[3];
    const float* Wk  = (const float*)d_in[4];
    const float* bk  = (const float*)d_in[5];
    const float* Wv  = (const float*)d_in[6];
    const float* bv  = (const float*)d_in[7];
    const float* Wo  = (const float*)d_in[8];
    const float* bo  = (const float*)d_in[9];
    const float* W1  = (const float*)d_in[10];
    const float* b1  = (const float*)d_in[11];
    const float* W2  = (const float*)d_in[12];
    const float* b2  = (const float*)d_in[13];
    const float* W3  = (const float*)d_in[14];
    const float* b3  = (const float*)d_in[15];  // softmax-invariant, folded out
    (void)b3;
    float* out = (float*)d_out;

    char* ws = (char*)d_ws;
    float* Q  = (float*)(ws + 0);                            // 768*256 f32
    float* A  = (float*)(ws + 786432);                       // 768*256 f32
    float* Kt = (float*)(ws + 1572864);                      // 256*768 f32
    unsigned short* Vtb = (unsigned short*)(ws + 2359296);   // 256*768 bf16
    float* S1 = (float*)(ws + 2752512);                      // 8*768*768 f32
    unsigned short* w2f  = (unsigned short*)(ws + 21626880); // 65536 bf16
    unsigned short* w3qg = (unsigned short*)(ws + 21757952); // 768*4096 bf16
    float* WoT = (float*)(ws + 28049408);                    // 256*256 f32
    // partial buffers: pv halves overlay Q/Kt (dead after s1_kernel)
    float* pv0g  = (float*)(ws + 0);                         // 768*256 f32 (over Q)
    float* pv1g  = (float*)(ws + 1572864);                   // 768*256 f32 (over Kt)
    float* psump = (float*)(ws + 28311552);                  // 1536*8 f32
    float* mp    = (float*)(ws + 28360704);                  // 1536*8 f32

    prep_kernel<<<1024, 256, 0, stream>>>(x, pos, Wq, bq, Wk, bk, Wv, bv,
                                          W1, W2, W3, Wo,
                                          Q, Kt, Vtb, A, w2f, WoT, w3qg);
    s1_kernel<<<288, 256, 0, stream>>>(Q, Kt, S1);
    fused_main_kernel<<<2 * N, 256, 0, stream>>>(A, S1, Vtb, w2f, w3qg,
                                                 b1, b2, pv0g, pv1g, psump, mp);
    combine_kernel<<<N, 256, 0, stream>>>(pv0g, pv1g, psump, mp, WoT, bo, out);
}